// Round 13
// baseline (400.943 us; speedup 1.0000x reference)
//
#include <hip/hip_runtime.h>
#include <stdint.h>

typedef unsigned short u16;
typedef short s8v __attribute__((ext_vector_type(8)));
typedef float f32x4 __attribute__((ext_vector_type(4)));

#define B_SZ 4
#define T_SEQ 2048
#define E_DIM 1024
#define H_NUM 16
#define HS 64
#define FF_DIM 4096
#define M_ROWS 8192  // B*T
// Q pre-scale: E^-0.5 * log2(e) -> QK^T scores arrive in log2 domain
#define QSCALE 0.0450842200f

__device__ __forceinline__ u16 f2bf(float f) {
    unsigned int u = __builtin_bit_cast(unsigned int, f);
    u += 0x7fffu + ((u >> 16) & 1u);
    return (u16)(u >> 16);
}

__device__ __forceinline__ float bf2f(u16 u) {
    unsigned int v = ((unsigned int)u) << 16;
    return __builtin_bit_cast(float, v);
}

__device__ __forceinline__ void async_copy16(const void* g, void* l) {
    __builtin_amdgcn_global_load_lds(
        (const __attribute__((address_space(1))) unsigned int*)g,
        (__attribute__((address_space(3))) unsigned int*)l, 16, 0, 0);
}

// ------- batched transpose + cast for the four 1024x1024 weights (Wq,Wk,Wv,Wp) -----
__global__ __launch_bounds__(256)
void transpose_cast4(const float* __restrict__ s0, const float* __restrict__ s1,
                     const float* __restrict__ s2, const float* __restrict__ s3,
                     u16* __restrict__ dqkv, u16* __restrict__ dp) {
    __shared__ float tile[32][33];
    const int zz = blockIdx.z;
    const float* src = (zz == 0) ? s0 : (zz == 1) ? s1 : (zz == 2) ? s2 : s3;
    u16* dst = (zz < 3) ? dqkv + (size_t)zz * 1048576 : dp;
    int n0 = blockIdx.x * 32, k0 = blockIdx.y * 32;
    int tx = threadIdx.x, ty = threadIdx.y;
#pragma unroll
    for (int i = 0; i < 4; i++)
        tile[ty + i * 8][tx] = src[(size_t)(k0 + ty + i * 8) * 1024 + n0 + tx];
    __syncthreads();
#pragma unroll
    for (int i = 0; i < 4; i++)
        dst[(size_t)(n0 + ty + i * 8) * 1024 + k0 + tx] = f2bf(tile[tx][ty + i * 8]);
}

// ------- merged transpose + cast for W1 [1024][4096] and W2 [4096][1024] -----------
__global__ __launch_bounds__(256)
void transpose_cast_w12(const float* __restrict__ W1, const float* __restrict__ W2,
                        u16* __restrict__ d1, u16* __restrict__ d2) {
    __shared__ float tile[32][33];
    const int zz = blockIdx.z;
    const float* src;
    u16* dst;
    int n0, k0, N, K;
    if (zz == 0) {  // W1: src [1024][4096] -> dst [4096][1024]
        src = W1; dst = d1; N = 4096; K = 1024;
        n0 = blockIdx.x * 32; k0 = blockIdx.y * 32;
    } else {        // W2: src [4096][1024] -> dst [1024][4096]
        src = W2; dst = d2; N = 1024; K = 4096;
        int idx = blockIdx.y * 128 + blockIdx.x;   // 0..4095
        n0 = (idx & 31) * 32; k0 = (idx >> 5) * 32;
    }
    int tx = threadIdx.x, ty = threadIdx.y;
#pragma unroll
    for (int i = 0; i < 4; i++)
        tile[ty + i * 8][tx] = src[(size_t)(k0 + ty + i * 8) * N + n0 + tx];
    __syncthreads();
#pragma unroll
    for (int i = 0; i < 4; i++)
        dst[(size_t)(n0 + ty + i * 8) * K + k0 + tx] = f2bf(tile[tx][ty + i * 8]);
}

// ---------------- V transpose per head: V [T][64] bf16 -> VT [64][T] bf16 ----------
__global__ __launch_bounds__(256)
void transpose_v(const u16* __restrict__ V, u16* __restrict__ VT) {
    __shared__ u16 tile[64][80];
    const int t0 = blockIdx.x * 64;
    const size_t hoff = (size_t)blockIdx.y * (T_SEQ * HS);
    const int r = threadIdx.x >> 2, c0 = (threadIdx.x & 3) * 16;
    const u16* src = V + hoff + (size_t)(t0 + r) * HS + c0;
    *(s8v*)&tile[r][c0] = *(const s8v*)src;
    *(s8v*)&tile[r][c0 + 8] = *(const s8v*)(src + 8);
    __syncthreads();
    u16 tmp[16];
#pragma unroll
    for (int e = 0; e < 16; e++) tmp[e] = tile[c0 + e][r];
    u16* dst = VT + hoff + (size_t)r * T_SEQ + t0 + c0;
    *(s8v*)dst = *(const s8v*)&tmp[0];
    *(s8v*)(dst + 8) = *(const s8v*)&tmp[8];
}

// ---------------- LayerNorm (E=1024) + bf16 cast, f32 input ------------------------
__global__ __launch_bounds__(256)
void ln_kernel(const float* __restrict__ x, const float* __restrict__ g,
               const float* __restrict__ b, u16* __restrict__ out) {
    int row = blockIdx.x;
    int tid = threadIdx.x;
    float4 v = ((const float4*)(x + (size_t)row * E_DIM))[tid];
    float s = v.x + v.y + v.z + v.w;
    float sq = v.x * v.x + v.y * v.y + v.z * v.z + v.w * v.w;
#pragma unroll
    for (int off = 32; off; off >>= 1) {
        s += __shfl_xor(s, off);
        sq += __shfl_xor(sq, off);
    }
    __shared__ float sh[8];
    int w = tid >> 6, lane = tid & 63;
    if (lane == 0) { sh[w] = s; sh[4 + w] = sq; }
    __syncthreads();
    s = sh[0] + sh[1] + sh[2] + sh[3];
    sq = sh[4] + sh[5] + sh[6] + sh[7];
    float mu = s * (1.f / E_DIM);
    float var = sq * (1.f / E_DIM) - mu * mu;
    float rs = rsqrtf(var + 1e-5f);
    float4 gv = ((const float4*)g)[tid];
    float4 bv = ((const float4*)b)[tid];
    ushort4 o;
    o.x = f2bf((v.x - mu) * rs * gv.x + bv.x);
    o.y = f2bf((v.y - mu) * rs * gv.y + bv.y);
    o.z = f2bf((v.z - mu) * rs * gv.z + bv.z);
    o.w = f2bf((v.w - mu) * rs * gv.w + bv.w);
    ((ushort4*)(out + (size_t)row * E_DIM))[tid] = o;
}

// ---------------- LayerNorm (E=1024) + bf16 cast, bf16 input (x2 diet) -------------
__global__ __launch_bounds__(256)
void ln_kernel_bf(const u16* __restrict__ x, const float* __restrict__ g,
                  const float* __restrict__ b, u16* __restrict__ out) {
    int row = blockIdx.x;
    int tid = threadIdx.x;
    ushort4 uv = ((const ushort4*)(x + (size_t)row * E_DIM))[tid];
    float4 v;
    v.x = bf2f(uv.x); v.y = bf2f(uv.y); v.z = bf2f(uv.z); v.w = bf2f(uv.w);
    float s = v.x + v.y + v.z + v.w;
    float sq = v.x * v.x + v.y * v.y + v.z * v.z + v.w * v.w;
#pragma unroll
    for (int off = 32; off; off >>= 1) {
        s += __shfl_xor(s, off);
        sq += __shfl_xor(sq, off);
    }
    __shared__ float sh[8];
    int w = tid >> 6, lane = tid & 63;
    if (lane == 0) { sh[w] = s; sh[4 + w] = sq; }
    __syncthreads();
    s = sh[0] + sh[1] + sh[2] + sh[3];
    sq = sh[4] + sh[5] + sh[6] + sh[7];
    float mu = s * (1.f / E_DIM);
    float var = sq * (1.f / E_DIM) - mu * mu;
    float rs = rsqrtf(var + 1e-5f);
    float4 gv = ((const float4*)g)[tid];
    float4 bv = ((const float4*)b)[tid];
    ushort4 o;
    o.x = f2bf((v.x - mu) * rs * gv.x + bv.x);
    o.y = f2bf((v.y - mu) * rs * gv.y + bv.y);
    o.z = f2bf((v.z - mu) * rs * gv.z + bv.z);
    o.w = f2bf((v.w - mu) * rs * gv.w + bv.w);
    ((ushort4*)(out + (size_t)row * E_DIM))[tid] = o;
}

// ---------------- GEMM 256x128 tile, BK=64, 8 waves, 3-deep pipeline (R5) ----------
// MODE 0: bf16 out, QKV head-split (Q pre-scaled by QSCALE for exp2 softmax)
// MODE 1: bf16 out, +bias, ReLU
// MODE 2: bf16 out = f2bf(resid_f32 + acc + bias)   (x2 residual diet)
template <int MODE>
__global__ __launch_bounds__(512)
void gemm_bt128(const u16* __restrict__ A, const u16* __restrict__ BT,
                int M, int N, int K,
                const float* __restrict__ bias, const float* __restrict__ resid,
                float* __restrict__ outf, u16* __restrict__ outb) {
    __shared__ __align__(16) u16 As[3][256 * 64];
    __shared__ __align__(16) u16 Bs[3][128 * 64];

    const int gx = gridDim.x;
    const int nwg = gx * gridDim.y;
    const int l = blockIdx.y * gx + blockIdx.x;
    const int sw = (l & 7) * (nwg >> 3) + (l >> 3);
    const int tRow = (sw / gx) * 256, tCol = (sw % gx) * 128;

    const int tid = threadIdx.x, w = tid >> 6, lane = tid & 63;
    const int wr = w >> 1, wc = w & 1, lr = lane & 15, hg = lane >> 4;
    const int nk = K >> 6;

    f32x4 z = {0.f, 0.f, 0.f, 0.f};
    f32x4 acc[4][4];
#pragma unroll
    for (int m = 0; m < 4; m++)
#pragma unroll
        for (int n = 0; n < 4; n++) acc[m][n] = z;

    auto STAGE_A = [&](int kt, int c) {
#pragma unroll
        for (int i = 0; i < 4; i++) {
            int chunk = i * 512 + tid;
            int row = chunk >> 3, j = chunk & 7;
            int js = (j ^ (row & 7)) << 3;
            async_copy16(A + (size_t)(tRow + row) * K + (kt << 6) + js,
                         &As[c][(i * 512 + w * 64) * 8]);
        }
    };
    auto STAGE_B = [&](int kt, int c) {
#pragma unroll
        for (int i = 0; i < 2; i++) {
            int chunk = i * 512 + tid;
            int row = chunk >> 3, j = chunk & 7;
            int js = (j ^ (row & 7)) << 3;
            async_copy16(BT + (size_t)(tCol + row) * K + (kt << 6) + js,
                         &Bs[c][(i * 512 + w * 64) * 8]);
        }
    };

    STAGE_A(0, 0); STAGE_B(0, 0);
    STAGE_A(1, 1); STAGE_B(1, 1);
    asm volatile("s_waitcnt vmcnt(6)" ::: "memory");
    asm volatile("s_barrier" ::: "memory");

    for (int t = 0; t < nk; ++t) {
        const int bu = t % 3, nx = (t + 2) % 3;
        const u16* Ab = &As[bu][0];
        const u16* Bb = &Bs[bu][0];
        const bool more = (t + 2 < nk);

        // ---- phase 0 ----
        s8v af0[2][2], bf[4][2];
#pragma unroll
        for (int m = 0; m < 2; m++)
#pragma unroll
            for (int kk = 0; kk < 2; kk++) {
                int r = wr * 64 + m * 16 + lr;
                af0[m][kk] = *(const s8v*)&Ab[r * 64 + (((kk * 4 + hg) ^ (r & 7)) << 3)];
            }
#pragma unroll
        for (int n = 0; n < 4; n++)
#pragma unroll
            for (int kk = 0; kk < 2; kk++) {
                int r = wc * 64 + n * 16 + lr;
                bf[n][kk] = *(const s8v*)&Bb[r * 64 + (((kk * 4 + hg) ^ (r & 7)) << 3)];
            }
        if (more) STAGE_A(t + 2, nx);
        asm volatile("s_barrier" ::: "memory");
        __builtin_amdgcn_s_setprio(1);
#pragma unroll
        for (int m = 0; m < 2; m++)
#pragma unroll
            for (int n = 0; n < 4; n++)
#pragma unroll
                for (int kk = 0; kk < 2; kk++)
                    acc[m][n] = __builtin_amdgcn_mfma_f32_16x16x32_bf16(
                        af0[m][kk], bf[n][kk], acc[m][n], 0, 0, 0);
        __builtin_amdgcn_s_setprio(0);
        asm volatile("s_barrier" ::: "memory");

        // ---- phase 1 ----
        s8v af1[2][2];
#pragma unroll
        for (int m = 0; m < 2; m++)
#pragma unroll
            for (int kk = 0; kk < 2; kk++) {
                int r = wr * 64 + (m + 2) * 16 + lr;
                af1[m][kk] = *(const s8v*)&Ab[r * 64 + (((kk * 4 + hg) ^ (r & 7)) << 3)];
            }
        if (more) STAGE_B(t + 2, nx);
        asm volatile("s_barrier" ::: "memory");
        __builtin_amdgcn_s_setprio(1);
#pragma unroll
        for (int m = 0; m < 2; m++)
#pragma unroll
            for (int n = 0; n < 4; n++)
#pragma unroll
                for (int kk = 0; kk < 2; kk++)
                    acc[m + 2][n] = __builtin_amdgcn_mfma_f32_16x16x32_bf16(
                        af1[m][kk], bf[n][kk], acc[m + 2][n], 0, 0, 0);
        __builtin_amdgcn_s_setprio(0);
        if (more) asm volatile("s_waitcnt vmcnt(6)" ::: "memory");
        else      asm volatile("s_waitcnt vmcnt(0)" ::: "memory");
        asm volatile("s_barrier" ::: "memory");
    }

#pragma unroll
    for (int m = 0; m < 4; m++)
#pragma unroll
        for (int n = 0; n < 4; n++)
#pragma unroll
            for (int r = 0; r < 4; r++) {
                int row = tRow + wr * 64 + m * 16 + hg * 4 + r;
                int col = tCol + wc * 64 + n * 16 + lr;
                float v = acc[m][n][r];
                if (MODE == 0) {
                    int type = col >> 10, c2 = col & 1023;
                    int h = c2 >> 6, d = c2 & 63;
                    int bb = row >> 11, tt = row & 2047;
                    if (type == 0) v *= QSCALE;  // Q pre-scale for exp2-domain softmax
                    outb[(size_t)type * 8388608 +
                         (((size_t)(bb * H_NUM + h) * T_SEQ + tt) << 6) + d] = f2bf(v);
                } else if (MODE == 1) {
                    v += bias[col];
                    v = fmaxf(v, 0.f);
                    outb[(size_t)row * N + col] = f2bf(v);
                } else {
                    outb[(size_t)row * N + col] =
                        f2bf(resid[(size_t)row * N + col] + v + bias[col]);
                }
            }
}

// ---------------- GEMM 256x256, deep-slack + PHASE-PIPELINED ds_reads --------------
// New this round: (a) ds_reads for phase p+1 issued during phase p (ping-pong frag
// sets afa/afb; B frags per tile parity bfa/bfb, t-loop unrolled x2 so all frag
// indexing is compile-time); (b) ONE barrier per phase (read/stage row-disjointness
// per phase verified; cross-wave read-vs-stage overlap keeps the same HBM-latency
// margin as the R9/m201 race-screened pattern); (c) vmcnt at p3 BEFORE the p3
// stage+reads: vmcnt(6) lands tile t+1's last half exactly when next-tile reads
// need it; stage_more? 6:0 drains fully once staging stops (protects final tiles).
// MODE 1: bf16 +bias ReLU; MODE 3: bf16 partial (z=0 -> outb, z=1 -> (u16*)outf).
template <int MODE>
__global__ __launch_bounds__(512)
void gemm_bt256(const u16* __restrict__ A, const u16* __restrict__ BT,
                int M, int N, int Kst, int klen,
                const float* __restrict__ bias, const float* __restrict__ resid,
                float* __restrict__ outf, u16* __restrict__ outb) {
    __shared__ __align__(16) u16 As[2][256 * 64];
    __shared__ __align__(16) u16 Bs[2][256 * 64];

    const int gx = gridDim.x;  // N/256
    const int nwg = gx * gridDim.y;
    const int l = blockIdx.y * gx + blockIdx.x;
    const int sw = (l & 7) * (nwg >> 3) + (l >> 3);
    const int tRow = (sw / gx) * 256, tCol = (sw % gx) * 256;
    const size_t koff = (size_t)blockIdx.z * klen;
    const u16* Az = A + koff;
    const u16* BTz = BT + koff;

    const int tid = threadIdx.x, w = tid >> 6, lane = tid & 63;
    const int wr = w >> 2, wc = w & 3, lr = lane & 15, hg = lane >> 4;
    const int nk = klen >> 6;

    f32x4 z = {0.f, 0.f, 0.f, 0.f};
    f32x4 acc[8][4];
#pragma unroll
    for (int m = 0; m < 8; m++)
#pragma unroll
        for (int n = 0; n < 4; n++) acc[m][n] = z;

    auto STAGE_A = [&](int kt, int c, int h) {
#pragma unroll
        for (int i = 0; i < 2; i++) {
            int chunk = h * 1024 + i * 512 + tid;
            int row = chunk >> 3, j = chunk & 7;
            int js = (j ^ (row & 7)) << 3;
            async_copy16(Az + (size_t)(tRow + row) * Kst + (kt << 6) + js,
                         &As[c][(h * 1024 + i * 512 + w * 64) * 8]);
        }
    };
    auto STAGE_B = [&](int kt, int c, int h) {
#pragma unroll
        for (int i = 0; i < 2; i++) {
            int chunk = h * 1024 + i * 512 + tid;
            int row = chunk >> 3, j = chunk & 7;
            int js = (j ^ (row & 7)) << 3;
            async_copy16(BTz + (size_t)(tCol + row) * Kst + (kt << 6) + js,
                         &Bs[c][(h * 1024 + i * 512 + w * 64) * 8]);
        }
    };

    // frag register sets (all indexing compile-time)
    s8v afa[2][2], afb[2][2];   // A-quarter ping-pong by phase parity
    s8v bfa[4][2], bfb[4][2];   // B frags by tile parity

    auto READ_A = [&](const u16* Ab, int p, s8v (&af)[2][2]) {
#pragma unroll
        for (int mm = 0; mm < 2; mm++)
#pragma unroll
            for (int kk = 0; kk < 2; kk++) {
                int r = (2 * p + mm) * 32 + wr * 16 + lr;
                af[mm][kk] = *(const s8v*)&Ab[r * 64 + (((kk * 4 + hg) ^ (r & 7)) << 3)];
            }
    };
    auto READ_B = [&](const u16* Bb, s8v (&bf)[4][2]) {
#pragma unroll
        for (int n = 0; n < 4; n++)
#pragma unroll
            for (int kk = 0; kk < 2; kk++) {
                int r = n * 64 + wc * 16 + lr;
                bf[n][kk] = *(const s8v*)&Bb[r * 64 + (((kk * 4 + hg) ^ (r & 7)) << 3)];
            }
    };

    // prologue: stage tiles 0,1; land tile0 (+B1h0); pre-read tile0 p0 frags
    STAGE_B(0, 0, 0); STAGE_B(0, 0, 1); STAGE_A(0, 0, 0); STAGE_A(0, 0, 1);
    STAGE_B(1, 1, 0); STAGE_B(1, 1, 1); STAGE_A(1, 1, 0); STAGE_A(1, 1, 1);
    asm volatile("s_waitcnt vmcnt(6)" ::: "memory");
    asm volatile("s_barrier" ::: "memory");
    READ_A(&As[0][0], 0, afa);
    READ_B(&Bs[0][0], bfa);

#define MFMA8(AF, BF, R0)                                                      \
    __builtin_amdgcn_s_setprio(1);                                             \
    _Pragma("unroll") for (int mm = 0; mm < 2; mm++)                           \
        _Pragma("unroll") for (int n = 0; n < 4; n++)                          \
            _Pragma("unroll") for (int kk = 0; kk < 2; kk++)                   \
                acc[R0 + mm][n] = __builtin_amdgcn_mfma_f32_16x16x32_bf16(     \
                    AF[mm][kk], BF[n][kk], acc[R0 + mm][n], 0, 0, 0);          \
    __builtin_amdgcn_s_setprio(0);

    auto TILE = [&](int t, s8v (&bf)[4][2], s8v (&bfn)[4][2]) {
        const int cur = t & 1;
        const u16* Ab = &As[cur][0];
        const u16* AbN = &As[cur ^ 1][0];
        const u16* BbN = &Bs[cur ^ 1][0];
        const bool stage_more = (t + 2 < nk);
        const bool read_more = (t + 1 < nk);

        // p0: MFMA rows 0-1 (frags pre-read); stage Bh0(t+2); read p1 frags
        MFMA8(afa, bf, 0);
        if (stage_more) STAGE_B(t + 2, cur, 0);
        READ_A(Ab, 1, afb);
        asm volatile("s_barrier" ::: "memory");

        // p1: MFMA rows 2-3; stage Bh1(t+2); read p2 frags
        MFMA8(afb, bf, 2);
        if (stage_more) STAGE_B(t + 2, cur, 1);
        READ_A(Ab, 2, afa);
        asm volatile("s_barrier" ::: "memory");

        // p2: MFMA rows 4-5; stage Ah0(t+2); read p3 frags
        MFMA8(afa, bf, 4);
        if (stage_more) STAGE_A(t + 2, cur, 0);
        READ_A(Ab, 3, afb);
        asm volatile("s_barrier" ::: "memory");

        // p3: MFMA rows 6-7; vmcnt BEFORE stage+reads (lands tile t+1);
        //     stage Ah1(t+2); read next tile's p0 frags
        MFMA8(afb, bf, 6);
        if (stage_more) asm volatile("s_waitcnt vmcnt(6)" ::: "memory");
        else            asm volatile("s_waitcnt vmcnt(0)" ::: "memory");
        if (stage_more) STAGE_A(t + 2, cur, 1);
        if (read_more) {
            READ_A(AbN, 0, afa);
            READ_B(BbN, bfn);
        }
        asm volatile("s_barrier" ::: "memory");
    };

    for (int tt = 0; tt < nk; tt += 2) {
        TILE(tt, bfa, bfb);
        TILE(tt + 1, bfb, bfa);
    }
#undef MFMA8

    u16* outp = outb;
    if (MODE == 3 && blockIdx.z == 1) outp = (u16*)outf;
#pragma unroll
    for (int m = 0; m < 8; m++)
#pragma unroll
        for (int n = 0; n < 4; n++)
#pragma unroll
            for (int r = 0; r < 4; r++) {
                int row = tRow + m * 32 + wr * 16 + hg * 4 + r;
                int col = tCol + n * 64 + wc * 16 + lr;
                float v = acc[m][n][r];
                if (MODE == 1) {
                    v += bias[col];
                    v = fmaxf(v, 0.f);
                    outp[(size_t)row * N + col] = f2bf(v);
                } else {
                    outp[(size_t)row * N + col] = f2bf(v);
                }
            }
}

// ------- split-K reduce: out_f32 = bf(p0) + bf(p1) + bf(resid) + bias --------------
__global__ __launch_bounds__(256)
void reduce_w2(const u16* __restrict__ p0, const u16* __restrict__ p1,
               const u16* __restrict__ resid, const float* __restrict__ bias,
               float* __restrict__ out) {
    const int total = M_ROWS * E_DIM / 4;
    for (int i = blockIdx.x * 256 + threadIdx.x; i < total; i += gridDim.x * 256) {
        ushort4 rr = ((const ushort4*)resid)[i];
        float4 bb = ((const float4*)bias)[i & 255];
        ushort4 a = ((const ushort4*)p0)[i];
        ushort4 c = ((const ushort4*)p1)[i];
        float4 o;
        o.x = bf2f(a.x) + bf2f(c.x) + bf2f(rr.x) + bb.x;
        o.y = bf2f(a.y) + bf2f(c.y) + bf2f(rr.y) + bb.y;
        o.z = bf2f(a.z) + bf2f(c.z) + bf2f(rr.z) + bb.z;
        o.w = bf2f(a.w) + bf2f(c.w) + bf2f(rr.w) + bb.w;
        ((float4*)out)[i] = o;
    }
}

// ---------------- causal flash attention, HS=64, 8 waves, paired q-tiles (R9) ------
// exp2-domain softmax (Q pre-scaled); deferred l-sum; cheap defer-max check;
// P->bf16 via truncation (P>0, rel err <= 2^-8).
__global__ __launch_bounds__(512)
void attn_kernel(const u16* __restrict__ Q, const u16* __restrict__ K,
                 const u16* __restrict__ VT, u16* __restrict__ O) {
    __shared__ u16 Ks[2][64 * 64];
    __shared__ u16 Vs[2][64 * 64];
    __shared__ u16 Pl[8][16 * 64];
    const int bh = blockIdx.y;
    const u16* Qh = Q + (size_t)bh * T_SEQ * HS;
    const u16* Kh = K + (size_t)bh * T_SEQ * HS;
    const u16* VTh = VT + (size_t)bh * T_SEQ * HS;
    const int tid = threadIdx.x, w = tid >> 6, lane = tid & 63;
    const int lr = lane & 15, hg = lane >> 4;
    const int swz = (lr & 7) << 3;
    const int bb = bh >> 4, hh = bh & 15;
    const f32x4 z = {0.f, 0.f, 0.f, 0.f};

    for (int half = 0; half < 2; ++half) {
        const int qt = half ? (15 - blockIdx.x) : blockIdx.x;
        const int qb = qt * 128;
        const int nt = 2 * qt + 2;

        s8v qf[2];
        {
            const int qrow = qb + w * 16 + lr;
            qf[0] = *(const s8v*)(Qh + (size_t)qrow * HS + hg * 8);
            qf[1] = *(const s8v*)(Qh + (size_t)qrow * HS + 32 + hg * 8);
        }
        f32x4 o[4] = {z, z, z, z};
        float m_run[4] = {-1e30f, -1e30f, -1e30f, -1e30f};
        float l_part[4] = {0.f, 0.f, 0.f, 0.f};

        auto STAGE = [&](int t, int c) {
            int chunk = tid;
            int row = chunk >> 3, j = chunk & 7;
            int js = (j ^ (row & 7)) << 3;
            async_copy16(Kh + (size_t)t * (64 * HS) + row * HS + js, &Ks[c][w * 512]);
            async_copy16(VTh + (size_t)row * T_SEQ + t * 64 + js, &Vs[c][w * 512]);
        };

        int cur = 0;
        STAGE(0, 0);
        __syncthreads();

        for (int t = 0; t < nt; ++t) {
            if (t + 1 < nt) STAGE(t + 1, cur ^ 1);

            f32x4 s[4];
            __builtin_amdgcn_s_setprio(1);
#pragma unroll
            for (int n = 0; n < 4; n++) {
                f32x4 a = z;
#pragma unroll
                for (int kc = 0; kc < 2; kc++) {
                    s8v bfr = *(const s8v*)&Ks[cur][((n * 16 + lr) * 64 + kc * 32 + hg * 8) ^ swz];
                    a = __builtin_amdgcn_mfma_f32_16x16x32_bf16(qf[kc], bfr, a, 0, 0, 0);
                }
                s[n] = a;
            }
            __builtin_amdgcn_s_setprio(0);
            const bool diag = (t >= nt - 2);
            if (diag) {
#pragma unroll
                for (int n = 0; n < 4; n++)
#pragma unroll
                    for (int r = 0; r < 4; r++)
                        if ((t * 64 + n * 16 + lr) > (qb + w * 16 + hg * 4 + r))
                            s[n][r] = -1e30f;
            }
            float d0[4][4];
            float dm = -1e30f;
#pragma unroll
            for (int n = 0; n < 4; n++)
#pragma unroll
                for (int r = 0; r < 4; r++) {
                    d0[n][r] = s[n][r] - m_run[r];
                    dm = fmaxf(dm, d0[n][r]);
                }
            if (__any(dm > 8.f)) {
                float pm[4];
#pragma unroll
                for (int r = 0; r < 4; r++) {
                    float m0 = fmaxf(fmaxf(s[0][r], s[1][r]), fmaxf(s[2][r], s[3][r]));
                    m0 = fmaxf(m0, __shfl_xor(m0, 1));
                    m0 = fmaxf(m0, __shfl_xor(m0, 2));
                    m0 = fmaxf(m0, __shfl_xor(m0, 4));
                    m0 = fmaxf(m0, __shfl_xor(m0, 8));
                    pm[r] = m0;
                }
#pragma unroll
                for (int r = 0; r < 4; r++) {
                    float mn = fmaxf(m_run[r], pm[r]);
                    float al = __builtin_amdgcn_exp2f(m_run[r] - mn);
                    m_run[r] = mn;
                    l_part[r] *= al;
                    o[0][r] *= al; o[1][r] *= al; o[2][r] *= al; o[3][r] *= al;
                }
#pragma unroll
                for (int n = 0; n < 4; n++)
#pragma unroll
                    for (int r = 0; r < 4; r++) d0[n][r] = s[n][r] - m_run[r];
            }
#pragma unroll
            for (int n = 0; n < 4; n++)
#pragma unroll
                for (int r = 0; r < 4; r++) {
                    float p = __builtin_amdgcn_exp2f(d0[n][r]);
                    s[n][r] = p;
                    l_part[r] += p;
                }
            u16* Pw = &Pl[w][0];
#pragma unroll
            for (int n = 0; n < 4; n++)
#pragma unroll
                for (int r = 0; r < 4; r++) {
                    int prow = hg * 4 + r;
                    float pv = s[n][r];
                    Pw[(prow * 64 + n * 16 + lr) ^ ((prow & 7) << 3)] =
                        (u16)(__builtin_bit_cast(unsigned int, pv) >> 16);  // trunc, P>0
                }
            asm volatile("s_waitcnt lgkmcnt(0)" ::: "memory");
            __builtin_amdgcn_s_setprio(1);
#pragma unroll
            for (int n = 0; n < 4; n++) {
#pragma unroll
                for (int kc = 0; kc < 2; kc++) {
                    s8v pa = *(const s8v*)&Pw[(lr * 64 + kc * 32 + hg * 8) ^ swz];
                    s8v vb = *(const s8v*)&Vs[cur][((n * 16 + lr) * 64 + kc * 32 + hg * 8) ^ swz];
                    o[n] = __builtin_amdgcn_mfma_f32_16x16x32_bf16(pa, vb, o[n], 0, 0, 0);
                }
            }
            __builtin_amdgcn_s_setprio(0);
            __syncthreads();
            cur ^= 1;
        }
        float rl[4];
#pragma unroll
        for (int r = 0; r < 4; r++) {
            float lsum = l_part[r];
            lsum += __shfl_xor(lsum, 1);
            lsum += __shfl_xor(lsum, 2);
            lsum += __shfl_xor(lsum, 4);
            lsum += __shfl_xor(lsum, 8);
            rl[r] = 1.f / lsum;
        }
#pragma unroll
        for (int n = 0; n < 4; n++)
#pragma unroll
            for (int r = 0; r < 4; r++) {
                int trow = qb + w * 16 + hg * 4 + r;
                O[((size_t)(bb * T_SEQ + trow)) * E_DIM + hh * HS + n * 16 + lr] =
                    f2bf(o[n][r] * rl[r]);
            }
    }
}

// ---------------- launch ----------------
extern "C" void kernel_launch(void* const* d_in, const int* in_sizes, int n_in,
                              void* d_out, int out_size, void* d_ws, size_t ws_size,
                              hipStream_t stream) {
    (void)in_sizes; (void)n_in; (void)out_size; (void)ws_size;
    const float* x  = (const float*)d_in[0];
    const float* Wq = (const float*)d_in[1];
    const float* Wk = (const float*)d_in[2];
    const float* Wv = (const float*)d_in[3];
    const float* Wp = (const float*)d_in[4];
    const float* bp = (const float*)d_in[5];
    const float* W1 = (const float*)d_in[6];
    const float* b1 = (const float*)d_in[7];
    const float* W2 = (const float*)d_in[8];
    const float* b2 = (const float*)d_in[9];
    const float* g1  = (const float*)d_in[10];
    const float* be1 = (const float*)d_in[11];
    const float* g2  = (const float*)d_in[12];
    const float* be2 = (const float*)d_in[13];

    char* ws = (char*)d_ws;
    u16* wqkv_t  = (u16*)(ws);                          // [3072][1024] bf16, 6 MB
    u16* wp_t    = (u16*)(ws + 6291456);                // [1024][1024], 2 MB
    u16* w1_t    = (u16*)(ws + 8388608);                // [4096][1024], 8 MB
    u16* w2_t    = (u16*)(ws + 16777216);               // [1024][4096], 8 MB
    u16* h_bf    = (u16*)(ws + 25165824);               // 16 MB (h1 / VT / h2 / part1)
    u16* q_bf    = (u16*)(ws + 41943040);               // [B,H,T,64] x3 + attn, 64 MB
    u16* attn_bf = q_bf + 3 * 8388608;
    u16* ff1     = q_bf;                                 // reuse 64 MB region
    u16* x2b     = (u16*)(ws + 109051904);              // [8192][1024] bf16, 16 MB
    u16* vt_bf   = h_bf;   // h1 consumed by QKV GEMM before transpose_v writes
    u16* part0   = (u16*)ws;  // W2 partial z0: wqkv/wp/w1t dead by W2 time (16 MB)
    u16* part1   = h_bf;      // W2 partial z1: h2 dead after W1 (16 MB)

    dim3 b32(32, 8);
    transpose_cast4<<<dim3(32, 32, 4), b32, 0, stream>>>(Wq, Wk, Wv, Wp, wqkv_t, wp_t);
    transpose_cast_w12<<<dim3(128, 32, 2), b32, 0, stream>>>(W1, W2, w1_t, w2_t);

    ln_kernel<<<M_ROWS, 256, 0, stream>>>(x, g1, be1, h_bf);
    gemm_bt128<0><<<dim3(24, 32), 512, 0, stream>>>(h_bf, wqkv_t, M_ROWS, 3072, 1024,
                                                    nullptr, nullptr, nullptr, q_bf);
    transpose_v<<<dim3(32, 64), 256, 0, stream>>>(q_bf + 2 * 8388608, vt_bf);
    attn_kernel<<<dim3(8, 64), 512, 0, stream>>>(q_bf, q_bf + 8388608, vt_bf, attn_bf);
    gemm_bt128<2><<<dim3(8, 32), 512, 0, stream>>>(attn_bf, wp_t, M_ROWS, 1024, 1024,
                                                   bp, x, nullptr, x2b);
    ln_kernel_bf<<<M_ROWS, 256, 0, stream>>>(x2b, g2, be2, h_bf);
    gemm_bt256<1><<<dim3(16, 32), 512, 0, stream>>>(h_bf, w1_t, M_ROWS, 4096, 1024, 1024,
                                                    b1, nullptr, nullptr, ff1);
    // W2 split-K x2 in ONE launch: grid (4,32,2) = 256 blocks = 1 full round
    gemm_bt256<3><<<dim3(4, 32, 2), 512, 0, stream>>>(ff1, w2_t, M_ROWS, 1024, 4096, 2048,
                                                      nullptr, nullptr, (float*)part1, part0);
    reduce_w2<<<2048, 256, 0, stream>>>(part0, part1, x2b, b2, (float*)d_out);
}

// Round 14
// 343.725 us; speedup vs baseline: 1.1665x; 1.1665x over previous
//
#include <hip/hip_runtime.h>
#include <stdint.h>

typedef unsigned short u16;
typedef short s8v __attribute__((ext_vector_type(8)));
typedef float f32x4 __attribute__((ext_vector_type(4)));

#define B_SZ 4
#define T_SEQ 2048
#define E_DIM 1024
#define H_NUM 16
#define HS 64
#define FF_DIM 4096
#define M_ROWS 8192  // B*T
// Q pre-scale: E^-0.5 * log2(e) -> QK^T scores arrive in log2 domain
#define QSCALE 0.0450842200f

__device__ __forceinline__ u16 f2bf(float f) {
    unsigned int u = __builtin_bit_cast(unsigned int, f);
    u += 0x7fffu + ((u >> 16) & 1u);
    return (u16)(u >> 16);
}

__device__ __forceinline__ float bf2f(u16 u) {
    unsigned int v = ((unsigned int)u) << 16;
    return __builtin_bit_cast(float, v);
}

__device__ __forceinline__ void async_copy16(const void* g, void* l) {
    __builtin_amdgcn_global_load_lds(
        (const __attribute__((address_space(1))) unsigned int*)g,
        (__attribute__((address_space(3))) unsigned int*)l, 16, 0, 0);
}

// ------- batched transpose + cast for the four 1024x1024 weights (Wq,Wk,Wv,Wp) -----
__global__ __launch_bounds__(256)
void transpose_cast4(const float* __restrict__ s0, const float* __restrict__ s1,
                     const float* __restrict__ s2, const float* __restrict__ s3,
                     u16* __restrict__ dqkv, u16* __restrict__ dp) {
    __shared__ float tile[32][33];
    const int zz = blockIdx.z;
    const float* src = (zz == 0) ? s0 : (zz == 1) ? s1 : (zz == 2) ? s2 : s3;
    u16* dst = (zz < 3) ? dqkv + (size_t)zz * 1048576 : dp;
    int n0 = blockIdx.x * 32, k0 = blockIdx.y * 32;
    int tx = threadIdx.x, ty = threadIdx.y;
#pragma unroll
    for (int i = 0; i < 4; i++)
        tile[ty + i * 8][tx] = src[(size_t)(k0 + ty + i * 8) * 1024 + n0 + tx];
    __syncthreads();
#pragma unroll
    for (int i = 0; i < 4; i++)
        dst[(size_t)(n0 + ty + i * 8) * 1024 + k0 + tx] = f2bf(tile[tx][ty + i * 8]);
}

// ------- merged transpose + cast for W1 [1024][4096] and W2 [4096][1024] -----------
__global__ __launch_bounds__(256)
void transpose_cast_w12(const float* __restrict__ W1, const float* __restrict__ W2,
                        u16* __restrict__ d1, u16* __restrict__ d2) {
    __shared__ float tile[32][33];
    const int zz = blockIdx.z;
    const float* src;
    u16* dst;
    int n0, k0, N, K;
    if (zz == 0) {  // W1: src [1024][4096] -> dst [4096][1024]
        src = W1; dst = d1; N = 4096; K = 1024;
        n0 = blockIdx.x * 32; k0 = blockIdx.y * 32;
    } else {        // W2: src [4096][1024] -> dst [1024][4096]
        src = W2; dst = d2; N = 1024; K = 4096;
        int idx = blockIdx.y * 128 + blockIdx.x;   // 0..4095
        n0 = (idx & 31) * 32; k0 = (idx >> 5) * 32;
    }
    int tx = threadIdx.x, ty = threadIdx.y;
#pragma unroll
    for (int i = 0; i < 4; i++)
        tile[ty + i * 8][tx] = src[(size_t)(k0 + ty + i * 8) * N + n0 + tx];
    __syncthreads();
#pragma unroll
    for (int i = 0; i < 4; i++)
        dst[(size_t)(n0 + ty + i * 8) * K + k0 + tx] = f2bf(tile[tx][ty + i * 8]);
}

// ---------------- V transpose per head: V [T][64] bf16 -> VT [64][T] bf16 ----------
__global__ __launch_bounds__(256)
void transpose_v(const u16* __restrict__ V, u16* __restrict__ VT) {
    __shared__ u16 tile[64][80];
    const int t0 = blockIdx.x * 64;
    const size_t hoff = (size_t)blockIdx.y * (T_SEQ * HS);
    const int r = threadIdx.x >> 2, c0 = (threadIdx.x & 3) * 16;
    const u16* src = V + hoff + (size_t)(t0 + r) * HS + c0;
    *(s8v*)&tile[r][c0] = *(const s8v*)src;
    *(s8v*)&tile[r][c0 + 8] = *(const s8v*)(src + 8);
    __syncthreads();
    u16 tmp[16];
#pragma unroll
    for (int e = 0; e < 16; e++) tmp[e] = tile[c0 + e][r];
    u16* dst = VT + hoff + (size_t)r * T_SEQ + t0 + c0;
    *(s8v*)dst = *(const s8v*)&tmp[0];
    *(s8v*)(dst + 8) = *(const s8v*)&tmp[8];
}

// ---------------- LayerNorm (E=1024) + bf16 cast, f32 input ------------------------
__global__ __launch_bounds__(256)
void ln_kernel(const float* __restrict__ x, const float* __restrict__ g,
               const float* __restrict__ b, u16* __restrict__ out) {
    int row = blockIdx.x;
    int tid = threadIdx.x;
    float4 v = ((const float4*)(x + (size_t)row * E_DIM))[tid];
    float s = v.x + v.y + v.z + v.w;
    float sq = v.x * v.x + v.y * v.y + v.z * v.z + v.w * v.w;
#pragma unroll
    for (int off = 32; off; off >>= 1) {
        s += __shfl_xor(s, off);
        sq += __shfl_xor(sq, off);
    }
    __shared__ float sh[8];
    int w = tid >> 6, lane = tid & 63;
    if (lane == 0) { sh[w] = s; sh[4 + w] = sq; }
    __syncthreads();
    s = sh[0] + sh[1] + sh[2] + sh[3];
    sq = sh[4] + sh[5] + sh[6] + sh[7];
    float mu = s * (1.f / E_DIM);
    float var = sq * (1.f / E_DIM) - mu * mu;
    float rs = rsqrtf(var + 1e-5f);
    float4 gv = ((const float4*)g)[tid];
    float4 bv = ((const float4*)b)[tid];
    ushort4 o;
    o.x = f2bf((v.x - mu) * rs * gv.x + bv.x);
    o.y = f2bf((v.y - mu) * rs * gv.y + bv.y);
    o.z = f2bf((v.z - mu) * rs * gv.z + bv.z);
    o.w = f2bf((v.w - mu) * rs * gv.w + bv.w);
    ((ushort4*)(out + (size_t)row * E_DIM))[tid] = o;
}

// ---------------- LayerNorm (E=1024) + bf16 cast, bf16 input (x2 diet) -------------
__global__ __launch_bounds__(256)
void ln_kernel_bf(const u16* __restrict__ x, const float* __restrict__ g,
                  const float* __restrict__ b, u16* __restrict__ out) {
    int row = blockIdx.x;
    int tid = threadIdx.x;
    ushort4 uv = ((const ushort4*)(x + (size_t)row * E_DIM))[tid];
    float4 v;
    v.x = bf2f(uv.x); v.y = bf2f(uv.y); v.z = bf2f(uv.z); v.w = bf2f(uv.w);
    float s = v.x + v.y + v.z + v.w;
    float sq = v.x * v.x + v.y * v.y + v.z * v.z + v.w * v.w;
#pragma unroll
    for (int off = 32; off; off >>= 1) {
        s += __shfl_xor(s, off);
        sq += __shfl_xor(sq, off);
    }
    __shared__ float sh[8];
    int w = tid >> 6, lane = tid & 63;
    if (lane == 0) { sh[w] = s; sh[4 + w] = sq; }
    __syncthreads();
    s = sh[0] + sh[1] + sh[2] + sh[3];
    sq = sh[4] + sh[5] + sh[6] + sh[7];
    float mu = s * (1.f / E_DIM);
    float var = sq * (1.f / E_DIM) - mu * mu;
    float rs = rsqrtf(var + 1e-5f);
    float4 gv = ((const float4*)g)[tid];
    float4 bv = ((const float4*)b)[tid];
    ushort4 o;
    o.x = f2bf((v.x - mu) * rs * gv.x + bv.x);
    o.y = f2bf((v.y - mu) * rs * gv.y + bv.y);
    o.z = f2bf((v.z - mu) * rs * gv.z + bv.z);
    o.w = f2bf((v.w - mu) * rs * gv.w + bv.w);
    ((ushort4*)(out + (size_t)row * E_DIM))[tid] = o;
}

// ---------------- GEMM 256x128 tile, BK=64, 8 waves, 3-deep pipeline (R5) ----------
// MODE 0: bf16 out, QKV head-split (Q pre-scaled by QSCALE for exp2 softmax)
// MODE 1: bf16 out, +bias, ReLU
// MODE 2: bf16 out = f2bf(resid_f32 + acc + bias)   (x2 residual diet)
template <int MODE>
__global__ __launch_bounds__(512)
void gemm_bt128(const u16* __restrict__ A, const u16* __restrict__ BT,
                int M, int N, int K,
                const float* __restrict__ bias, const float* __restrict__ resid,
                float* __restrict__ outf, u16* __restrict__ outb) {
    __shared__ __align__(16) u16 As[3][256 * 64];
    __shared__ __align__(16) u16 Bs[3][128 * 64];

    const int gx = gridDim.x;
    const int nwg = gx * gridDim.y;
    const int l = blockIdx.y * gx + blockIdx.x;
    const int sw = (l & 7) * (nwg >> 3) + (l >> 3);
    const int tRow = (sw / gx) * 256, tCol = (sw % gx) * 128;

    const int tid = threadIdx.x, w = tid >> 6, lane = tid & 63;
    const int wr = w >> 1, wc = w & 1, lr = lane & 15, hg = lane >> 4;
    const int nk = K >> 6;

    f32x4 z = {0.f, 0.f, 0.f, 0.f};
    f32x4 acc[4][4];
#pragma unroll
    for (int m = 0; m < 4; m++)
#pragma unroll
        for (int n = 0; n < 4; n++) acc[m][n] = z;

    auto STAGE_A = [&](int kt, int c) {
#pragma unroll
        for (int i = 0; i < 4; i++) {
            int chunk = i * 512 + tid;
            int row = chunk >> 3, j = chunk & 7;
            int js = (j ^ (row & 7)) << 3;
            async_copy16(A + (size_t)(tRow + row) * K + (kt << 6) + js,
                         &As[c][(i * 512 + w * 64) * 8]);
        }
    };
    auto STAGE_B = [&](int kt, int c) {
#pragma unroll
        for (int i = 0; i < 2; i++) {
            int chunk = i * 512 + tid;
            int row = chunk >> 3, j = chunk & 7;
            int js = (j ^ (row & 7)) << 3;
            async_copy16(BT + (size_t)(tCol + row) * K + (kt << 6) + js,
                         &Bs[c][(i * 512 + w * 64) * 8]);
        }
    };

    STAGE_A(0, 0); STAGE_B(0, 0);
    STAGE_A(1, 1); STAGE_B(1, 1);
    asm volatile("s_waitcnt vmcnt(6)" ::: "memory");
    asm volatile("s_barrier" ::: "memory");

    for (int t = 0; t < nk; ++t) {
        const int bu = t % 3, nx = (t + 2) % 3;
        const u16* Ab = &As[bu][0];
        const u16* Bb = &Bs[bu][0];
        const bool more = (t + 2 < nk);

        // ---- phase 0 ----
        s8v af0[2][2], bf[4][2];
#pragma unroll
        for (int m = 0; m < 2; m++)
#pragma unroll
            for (int kk = 0; kk < 2; kk++) {
                int r = wr * 64 + m * 16 + lr;
                af0[m][kk] = *(const s8v*)&Ab[r * 64 + (((kk * 4 + hg) ^ (r & 7)) << 3)];
            }
#pragma unroll
        for (int n = 0; n < 4; n++)
#pragma unroll
            for (int kk = 0; kk < 2; kk++) {
                int r = wc * 64 + n * 16 + lr;
                bf[n][kk] = *(const s8v*)&Bb[r * 64 + (((kk * 4 + hg) ^ (r & 7)) << 3)];
            }
        if (more) STAGE_A(t + 2, nx);
        asm volatile("s_barrier" ::: "memory");
        __builtin_amdgcn_s_setprio(1);
#pragma unroll
        for (int m = 0; m < 2; m++)
#pragma unroll
            for (int n = 0; n < 4; n++)
#pragma unroll
                for (int kk = 0; kk < 2; kk++)
                    acc[m][n] = __builtin_amdgcn_mfma_f32_16x16x32_bf16(
                        af0[m][kk], bf[n][kk], acc[m][n], 0, 0, 0);
        __builtin_amdgcn_s_setprio(0);
        asm volatile("s_barrier" ::: "memory");

        // ---- phase 1 ----
        s8v af1[2][2];
#pragma unroll
        for (int m = 0; m < 2; m++)
#pragma unroll
            for (int kk = 0; kk < 2; kk++) {
                int r = wr * 64 + (m + 2) * 16 + lr;
                af1[m][kk] = *(const s8v*)&Ab[r * 64 + (((kk * 4 + hg) ^ (r & 7)) << 3)];
            }
        if (more) STAGE_B(t + 2, nx);
        asm volatile("s_barrier" ::: "memory");
        __builtin_amdgcn_s_setprio(1);
#pragma unroll
        for (int m = 0; m < 2; m++)
#pragma unroll
            for (int n = 0; n < 4; n++)
#pragma unroll
                for (int kk = 0; kk < 2; kk++)
                    acc[m + 2][n] = __builtin_amdgcn_mfma_f32_16x16x32_bf16(
                        af1[m][kk], bf[n][kk], acc[m + 2][n], 0, 0, 0);
        __builtin_amdgcn_s_setprio(0);
        if (more) asm volatile("s_waitcnt vmcnt(6)" ::: "memory");
        else      asm volatile("s_waitcnt vmcnt(0)" ::: "memory");
        asm volatile("s_barrier" ::: "memory");
    }

#pragma unroll
    for (int m = 0; m < 4; m++)
#pragma unroll
        for (int n = 0; n < 4; n++)
#pragma unroll
            for (int r = 0; r < 4; r++) {
                int row = tRow + wr * 64 + m * 16 + hg * 4 + r;
                int col = tCol + wc * 64 + n * 16 + lr;
                float v = acc[m][n][r];
                if (MODE == 0) {
                    int type = col >> 10, c2 = col & 1023;
                    int h = c2 >> 6, d = c2 & 63;
                    int bb = row >> 11, tt = row & 2047;
                    if (type == 0) v *= QSCALE;  // Q pre-scale for exp2-domain softmax
                    outb[(size_t)type * 8388608 +
                         (((size_t)(bb * H_NUM + h) * T_SEQ + tt) << 6) + d] = f2bf(v);
                } else if (MODE == 1) {
                    v += bias[col];
                    v = fmaxf(v, 0.f);
                    outb[(size_t)row * N + col] = f2bf(v);
                } else {
                    outb[(size_t)row * N + col] =
                        f2bf(resid[(size_t)row * N + col] + v + bias[col]);
                }
            }
}

// ---------------- GEMM 256x256 tile, BK=64, 8 waves (2Mx4N), deep-slack (R9) -------
// Kst = row stride; klen = K range per z-slice (A/BT advanced by z*klen).
// MODE 1: bf16 +bias ReLU; MODE 3: bf16 partial (z=0 -> outb, z=1 -> (u16*)outf).
template <int MODE>
__global__ __launch_bounds__(512)
void gemm_bt256(const u16* __restrict__ A, const u16* __restrict__ BT,
                int M, int N, int Kst, int klen,
                const float* __restrict__ bias, const float* __restrict__ resid,
                float* __restrict__ outf, u16* __restrict__ outb) {
    __shared__ __align__(16) u16 As[2][256 * 64];
    __shared__ __align__(16) u16 Bs[2][256 * 64];

    const int gx = gridDim.x;  // N/256
    const int nwg = gx * gridDim.y;
    const int l = blockIdx.y * gx + blockIdx.x;
    const int sw = (l & 7) * (nwg >> 3) + (l >> 3);
    const int tRow = (sw / gx) * 256, tCol = (sw % gx) * 256;
    const size_t koff = (size_t)blockIdx.z * klen;
    const u16* Az = A + koff;
    const u16* BTz = BT + koff;

    const int tid = threadIdx.x, w = tid >> 6, lane = tid & 63;
    const int wr = w >> 2, wc = w & 3, lr = lane & 15, hg = lane >> 4;
    const int nk = klen >> 6;

    f32x4 z = {0.f, 0.f, 0.f, 0.f};
    f32x4 acc[8][4];
#pragma unroll
    for (int m = 0; m < 8; m++)
#pragma unroll
        for (int n = 0; n < 4; n++) acc[m][n] = z;

    // stage half h (rows [h*128, h*128+128)) of a 256x64 K-tile; 2 loads/thread
    auto STAGE_A = [&](int kt, int c, int h) {
#pragma unroll
        for (int i = 0; i < 2; i++) {
            int chunk = h * 1024 + i * 512 + tid;
            int row = chunk >> 3, j = chunk & 7;
            int js = (j ^ (row & 7)) << 3;
            async_copy16(Az + (size_t)(tRow + row) * Kst + (kt << 6) + js,
                         &As[c][(h * 1024 + i * 512 + w * 64) * 8]);
        }
    };
    auto STAGE_B = [&](int kt, int c, int h) {
#pragma unroll
        for (int i = 0; i < 2; i++) {
            int chunk = h * 1024 + i * 512 + tid;
            int row = chunk >> 3, j = chunk & 7;
            int js = (j ^ (row & 7)) << 3;
            async_copy16(BTz + (size_t)(tCol + row) * Kst + (kt << 6) + js,
                         &Bs[c][(h * 1024 + i * 512 + w * 64) * 8]);
        }
    };

    // prologue: K-tiles 0,1 (16 loads/thread); vmcnt(6) lands buf0 fully + B1h0
    STAGE_B(0, 0, 0); STAGE_B(0, 0, 1); STAGE_A(0, 0, 0); STAGE_A(0, 0, 1);
    STAGE_B(1, 1, 0); STAGE_B(1, 1, 1); STAGE_A(1, 1, 0); STAGE_A(1, 1, 1);
    asm volatile("s_waitcnt vmcnt(6)" ::: "memory");
    asm volatile("s_barrier" ::: "memory");

    for (int t = 0; t < nk; ++t) {
        const int cur = t & 1;  // t+2 has same parity -> stage into cur
        const u16* Ab = &As[cur][0];
        const u16* Bb = &Bs[cur][0];
        const bool more = (t + 2 < nk);

        s8v bf[4][2];
#pragma unroll
        for (int p = 0; p < 4; p++) {
            // ds-read this phase's A quarter (rows [64p, 64p+64))
            s8v af[2][2];
#pragma unroll
            for (int mm = 0; mm < 2; mm++)
#pragma unroll
                for (int kk = 0; kk < 2; kk++) {
                    int r = (2 * p + mm) * 32 + wr * 16 + lr;
                    af[mm][kk] = *(const s8v*)&Ab[r * 64 + (((kk * 4 + hg) ^ (r & 7)) << 3)];
                }
            if (p == 0) {
#pragma unroll
                for (int n = 0; n < 4; n++)
#pragma unroll
                    for (int kk = 0; kk < 2; kk++) {
                        int r = n * 64 + wc * 16 + lr;
                        bf[n][kk] = *(const s8v*)&Bb[r * 64 + (((kk * 4 + hg) ^ (r & 7)) << 3)];
                    }
            }
            // stage one half of tile t+2 into THIS buffer (consumed halves are dead)
            if (more) {
                if (p == 0) STAGE_B(t + 2, cur, 0);
                else if (p == 1) STAGE_B(t + 2, cur, 1);
                else if (p == 2) STAGE_A(t + 2, cur, 0);
                else STAGE_A(t + 2, cur, 1);
            }
            asm volatile("s_barrier" ::: "memory");
            __builtin_amdgcn_s_setprio(1);
#pragma unroll
            for (int mm = 0; mm < 2; mm++)
#pragma unroll
                for (int n = 0; n < 4; n++)
#pragma unroll
                    for (int kk = 0; kk < 2; kk++)
                        acc[2 * p + mm][n] = __builtin_amdgcn_mfma_f32_16x16x32_bf16(
                            af[mm][kk], bf[n][kk], acc[2 * p + mm][n], 0, 0, 0);
            __builtin_amdgcn_s_setprio(0);
            if (p == 3) {
                // once per K-tile: lands tile t+1 completely (issued 4-7 phases ago)
                if (more) asm volatile("s_waitcnt vmcnt(6)" ::: "memory");
                else      asm volatile("s_waitcnt vmcnt(0)" ::: "memory");
            }
            asm volatile("s_barrier" ::: "memory");
        }
    }

    u16* outp = outb;
    if (MODE == 3 && blockIdx.z == 1) outp = (u16*)outf;
#pragma unroll
    for (int m = 0; m < 8; m++)
#pragma unroll
        for (int n = 0; n < 4; n++)
#pragma unroll
            for (int r = 0; r < 4; r++) {
                int row = tRow + m * 32 + wr * 16 + hg * 4 + r;
                int col = tCol + n * 64 + wc * 16 + lr;
                float v = acc[m][n][r];
                if (MODE == 1) {
                    v += bias[col];
                    v = fmaxf(v, 0.f);
                    outp[(size_t)row * N + col] = f2bf(v);
                } else {
                    outp[(size_t)row * N + col] = f2bf(v);
                }
            }
}

// ------- split-K reduce: out_f32 = bf(p0) + bf(p1) + bf(resid) + bias --------------
__global__ __launch_bounds__(256)
void reduce_w2(const u16* __restrict__ p0, const u16* __restrict__ p1,
               const u16* __restrict__ resid, const float* __restrict__ bias,
               float* __restrict__ out) {
    const int total = M_ROWS * E_DIM / 4;
    for (int i = blockIdx.x * 256 + threadIdx.x; i < total; i += gridDim.x * 256) {
        ushort4 rr = ((const ushort4*)resid)[i];
        float4 bb = ((const float4*)bias)[i & 255];
        ushort4 a = ((const ushort4*)p0)[i];
        ushort4 c = ((const ushort4*)p1)[i];
        float4 o;
        o.x = bf2f(a.x) + bf2f(c.x) + bf2f(rr.x) + bb.x;
        o.y = bf2f(a.y) + bf2f(c.y) + bf2f(rr.y) + bb.y;
        o.z = bf2f(a.z) + bf2f(c.z) + bf2f(rr.z) + bb.z;
        o.w = bf2f(a.w) + bf2f(c.w) + bf2f(rr.w) + bb.w;
        ((float4*)out)[i] = o;
    }
}

// ---------------- causal flash attention, HS=64, 8 waves, paired q-tiles ----------
// exp2-domain softmax (Q pre-scaled), m_run init 0 (not -1e30: avoids catastrophic
// cancellation in d0). NEW: sum-doubles-as-check — p=exp2(d0) computed eagerly,
// per-lane tree sums sm[] (needed for l_part anyway) serve as the overflow check
// (sum >= max, never false-negative; NaN/inf-safe via !(x<=)); removes the serial
// 16-deep fmax chain. Deferral bound 2^11 per entry (~= old e^8).
__global__ __launch_bounds__(512)
void attn_kernel(const u16* __restrict__ Q, const u16* __restrict__ K,
                 const u16* __restrict__ VT, u16* __restrict__ O) {
    __shared__ u16 Ks[2][64 * 64];
    __shared__ u16 Vs[2][64 * 64];
    __shared__ u16 Pl[8][16 * 64];
    const int bh = blockIdx.y;
    const u16* Qh = Q + (size_t)bh * T_SEQ * HS;
    const u16* Kh = K + (size_t)bh * T_SEQ * HS;
    const u16* VTh = VT + (size_t)bh * T_SEQ * HS;
    const int tid = threadIdx.x, w = tid >> 6, lane = tid & 63;
    const int lr = lane & 15, hg = lane >> 4;
    const int swz = (lr & 7) << 3;
    const int bb = bh >> 4, hh = bh & 15;
    const f32x4 z = {0.f, 0.f, 0.f, 0.f};

    for (int half = 0; half < 2; ++half) {
        const int qt = half ? (15 - blockIdx.x) : blockIdx.x;
        const int qb = qt * 128;
        const int nt = 2 * qt + 2;

        s8v qf[2];
        {
            const int qrow = qb + w * 16 + lr;
            qf[0] = *(const s8v*)(Qh + (size_t)qrow * HS + hg * 8);
            qf[1] = *(const s8v*)(Qh + (size_t)qrow * HS + 32 + hg * 8);
        }
        f32x4 o[4] = {z, z, z, z};
        float m_run[4] = {0.f, 0.f, 0.f, 0.f};   // base-0 shift; grows on trigger
        float l_part[4] = {0.f, 0.f, 0.f, 0.f};

        auto STAGE = [&](int t, int c) {
            int chunk = tid;
            int row = chunk >> 3, j = chunk & 7;
            int js = (j ^ (row & 7)) << 3;
            async_copy16(Kh + (size_t)t * (64 * HS) + row * HS + js, &Ks[c][w * 512]);
            async_copy16(VTh + (size_t)row * T_SEQ + t * 64 + js, &Vs[c][w * 512]);
        };

        int cur = 0;
        STAGE(0, 0);
        __syncthreads();

        for (int t = 0; t < nt; ++t) {
            if (t + 1 < nt) STAGE(t + 1, cur ^ 1);

            f32x4 s[4];
            __builtin_amdgcn_s_setprio(1);
#pragma unroll
            for (int n = 0; n < 4; n++) {
                f32x4 a = z;
#pragma unroll
                for (int kc = 0; kc < 2; kc++) {
                    s8v bfr = *(const s8v*)&Ks[cur][((n * 16 + lr) * 64 + kc * 32 + hg * 8) ^ swz];
                    a = __builtin_amdgcn_mfma_f32_16x16x32_bf16(qf[kc], bfr, a, 0, 0, 0);
                }
                s[n] = a;
            }
            __builtin_amdgcn_s_setprio(0);
            const bool diag = (t >= nt - 2);
            if (diag) {
#pragma unroll
                for (int n = 0; n < 4; n++)
#pragma unroll
                    for (int r = 0; r < 4; r++)
                        if ((t * 64 + n * 16 + lr) > (qb + w * 16 + hg * 4 + r))
                            s[n][r] = -1e30f;
            }
            // eager exp2 + tree sums; sums double as the defer-max check
            float d0[4][4], p4[4][4];
#pragma unroll
            for (int n = 0; n < 4; n++)
#pragma unroll
                for (int r = 0; r < 4; r++) {
                    d0[n][r] = s[n][r] - m_run[r];
                    p4[n][r] = __builtin_amdgcn_exp2f(d0[n][r]);
                }
            float sm[4];
#pragma unroll
            for (int r = 0; r < 4; r++)
                sm[r] = (p4[0][r] + p4[1][r]) + (p4[2][r] + p4[3][r]);
            float smax = fmaxf(fmaxf(sm[0], sm[1]), fmaxf(sm[2], sm[3]));
            if (__any(!(smax <= 2048.f))) {
                // triggered: proper per-row max (d0 domain), shift >= 0, rescale
                float pm[4];
#pragma unroll
                for (int r = 0; r < 4; r++) {
                    float m0 = fmaxf(fmaxf(d0[0][r], d0[1][r]), fmaxf(d0[2][r], d0[3][r]));
                    m0 = fmaxf(m0, __shfl_xor(m0, 1));
                    m0 = fmaxf(m0, __shfl_xor(m0, 2));
                    m0 = fmaxf(m0, __shfl_xor(m0, 4));
                    m0 = fmaxf(m0, __shfl_xor(m0, 8));
                    pm[r] = fmaxf(m0, 0.f);
                }
#pragma unroll
                for (int r = 0; r < 4; r++) {
                    float al = __builtin_amdgcn_exp2f(-pm[r]);
                    m_run[r] += pm[r];
                    l_part[r] *= al;
                    o[0][r] *= al; o[1][r] *= al; o[2][r] *= al; o[3][r] *= al;
                }
#pragma unroll
                for (int n = 0; n < 4; n++)
#pragma unroll
                    for (int r = 0; r < 4; r++)
                        p4[n][r] = __builtin_amdgcn_exp2f(d0[n][r] - pm[r]);
#pragma unroll
                for (int r = 0; r < 4; r++)
                    sm[r] = (p4[0][r] + p4[1][r]) + (p4[2][r] + p4[3][r]);
            }
#pragma unroll
            for (int r = 0; r < 4; r++) l_part[r] += sm[r];
            u16* Pw = &Pl[w][0];
#pragma unroll
            for (int n = 0; n < 4; n++)
#pragma unroll
                for (int r = 0; r < 4; r++) {
                    int prow = hg * 4 + r;
                    Pw[(prow * 64 + n * 16 + lr) ^ ((prow & 7) << 3)] =
                        (u16)(__builtin_bit_cast(unsigned int, p4[n][r]) >> 16);  // trunc, P>0
                }
            asm volatile("s_waitcnt lgkmcnt(0)" ::: "memory");
            __builtin_amdgcn_s_setprio(1);
#pragma unroll
            for (int n = 0; n < 4; n++) {
#pragma unroll
                for (int kc = 0; kc < 2; kc++) {
                    s8v pa = *(const s8v*)&Pw[(lr * 64 + kc * 32 + hg * 8) ^ swz];
                    s8v vb = *(const s8v*)&Vs[cur][((n * 16 + lr) * 64 + kc * 32 + hg * 8) ^ swz];
                    o[n] = __builtin_amdgcn_mfma_f32_16x16x32_bf16(pa, vb, o[n], 0, 0, 0);
                }
            }
            __builtin_amdgcn_s_setprio(0);
            __syncthreads();
            cur ^= 1;
        }
        float rl[4];
#pragma unroll
        for (int r = 0; r < 4; r++) {
            float lsum = l_part[r];
            lsum += __shfl_xor(lsum, 1);
            lsum += __shfl_xor(lsum, 2);
            lsum += __shfl_xor(lsum, 4);
            lsum += __shfl_xor(lsum, 8);
            rl[r] = 1.f / lsum;
        }
#pragma unroll
        for (int n = 0; n < 4; n++)
#pragma unroll
            for (int r = 0; r < 4; r++) {
                int trow = qb + w * 16 + hg * 4 + r;
                O[((size_t)(bb * T_SEQ + trow)) * E_DIM + hh * HS + n * 16 + lr] =
                    f2bf(o[n][r] * rl[r]);
            }
    }
}

// ---------------- launch ----------------
extern "C" void kernel_launch(void* const* d_in, const int* in_sizes, int n_in,
                              void* d_out, int out_size, void* d_ws, size_t ws_size,
                              hipStream_t stream) {
    (void)in_sizes; (void)n_in; (void)out_size; (void)ws_size;
    const float* x  = (const float*)d_in[0];
    const float* Wq = (const float*)d_in[1];
    const float* Wk = (const float*)d_in[2];
    const float* Wv = (const float*)d_in[3];
    const float* Wp = (const float*)d_in[4];
    const float* bp = (const float*)d_in[5];
    const float* W1 = (const float*)d_in[6];
    const float* b1 = (const float*)d_in[7];
    const float* W2 = (const float*)d_in[8];
    const float* b2 = (const float*)d_in[9];
    const float* g1  = (const float*)d_in[10];
    const float* be1 = (const float*)d_in[11];
    const float* g2  = (const float*)d_in[12];
    const float* be2 = (const float*)d_in[13];

    char* ws = (char*)d_ws;
    u16* wqkv_t  = (u16*)(ws);                          // [3072][1024] bf16, 6 MB
    u16* wp_t    = (u16*)(ws + 6291456);                // [1024][1024], 2 MB
    u16* w1_t    = (u16*)(ws + 8388608);                // [4096][1024], 8 MB
    u16* w2_t    = (u16*)(ws + 16777216);               // [1024][4096], 8 MB
    u16* h_bf    = (u16*)(ws + 25165824);               // 16 MB (h1 / VT / h2 / part1)
    u16* q_bf    = (u16*)(ws + 41943040);               // [B,H,T,64] x3 + attn, 64 MB
    u16* attn_bf = q_bf + 3 * 8388608;
    u16* ff1     = q_bf;                                 // reuse 64 MB region
    u16* x2b     = (u16*)(ws + 109051904);              // [8192][1024] bf16, 16 MB
    u16* vt_bf   = h_bf;   // h1 consumed by QKV GEMM before transpose_v writes
    u16* part0   = (u16*)ws;  // W2 partial z0: wqkv/wp/w1t dead by W2 time (16 MB)
    u16* part1   = h_bf;      // W2 partial z1: h2 dead after W1 (16 MB)

    dim3 b32(32, 8);
    transpose_cast4<<<dim3(32, 32, 4), b32, 0, stream>>>(Wq, Wk, Wv, Wp, wqkv_t, wp_t);
    transpose_cast_w12<<<dim3(128, 32, 2), b32, 0, stream>>>(W1, W2, w1_t, w2_t);

    ln_kernel<<<M_ROWS, 256, 0, stream>>>(x, g1, be1, h_bf);
    gemm_bt128<0><<<dim3(24, 32), 512, 0, stream>>>(h_bf, wqkv_t, M_ROWS, 3072, 1024,
                                                    nullptr, nullptr, nullptr, q_bf);
    transpose_v<<<dim3(32, 64), 256, 0, stream>>>(q_bf + 2 * 8388608, vt_bf);
    attn_kernel<<<dim3(8, 64), 512, 0, stream>>>(q_bf, q_bf + 8388608, vt_bf, attn_bf);
    gemm_bt128<2><<<dim3(8, 32), 512, 0, stream>>>(attn_bf, wp_t, M_ROWS, 1024, 1024,
                                                   bp, x, nullptr, x2b);
    ln_kernel_bf<<<M_ROWS, 256, 0, stream>>>(x2b, g2, be2, h_bf);
    gemm_bt256<1><<<dim3(16, 32), 512, 0, stream>>>(h_bf, w1_t, M_ROWS, 4096, 1024, 1024,
                                                    b1, nullptr, nullptr, ff1);
    // W2 split-K x2 in ONE launch: grid (4,32,2) = 256 blocks = 1 full round
    gemm_bt256<3><<<dim3(4, 32, 2), 512, 0, stream>>>(ff1, w2_t, M_ROWS, 1024, 4096, 2048,
                                                      nullptr, nullptr, (float*)part1, part0);
    reduce_w2<<<2048, 256, 0, stream>>>(part0, part1, x2b, b2, (float*)d_out);
}

// Round 15
// 338.904 us; speedup vs baseline: 1.1831x; 1.0142x over previous
//
#include <hip/hip_runtime.h>
#include <stdint.h>

typedef unsigned short u16;
typedef short s8v __attribute__((ext_vector_type(8)));
typedef float f32x4 __attribute__((ext_vector_type(4)));

#define B_SZ 4
#define T_SEQ 2048
#define E_DIM 1024
#define H_NUM 16
#define HS 64
#define FF_DIM 4096
#define M_ROWS 8192  // B*T
// Q pre-scale: E^-0.5 * log2(e) -> QK^T scores arrive in log2 domain
#define QSCALE 0.0450842200f

__device__ __forceinline__ u16 f2bf(float f) {
    unsigned int u = __builtin_bit_cast(unsigned int, f);
    u += 0x7fffu + ((u >> 16) & 1u);
    return (u16)(u >> 16);
}

__device__ __forceinline__ float bf2f(u16 u) {
    unsigned int v = ((unsigned int)u) << 16;
    return __builtin_bit_cast(float, v);
}

__device__ __forceinline__ void async_copy16(const void* g, void* l) {
    __builtin_amdgcn_global_load_lds(
        (const __attribute__((address_space(1))) unsigned int*)g,
        (__attribute__((address_space(3))) unsigned int*)l, 16, 0, 0);
}

// ------- batched transpose + cast for the four 1024x1024 weights (Wq,Wk,Wv,Wp) -----
__global__ __launch_bounds__(256)
void transpose_cast4(const float* __restrict__ s0, const float* __restrict__ s1,
                     const float* __restrict__ s2, const float* __restrict__ s3,
                     u16* __restrict__ dqkv, u16* __restrict__ dp) {
    __shared__ float tile[32][33];
    const int zz = blockIdx.z;
    const float* src = (zz == 0) ? s0 : (zz == 1) ? s1 : (zz == 2) ? s2 : s3;
    u16* dst = (zz < 3) ? dqkv + (size_t)zz * 1048576 : dp;
    int n0 = blockIdx.x * 32, k0 = blockIdx.y * 32;
    int tx = threadIdx.x, ty = threadIdx.y;
#pragma unroll
    for (int i = 0; i < 4; i++)
        tile[ty + i * 8][tx] = src[(size_t)(k0 + ty + i * 8) * 1024 + n0 + tx];
    __syncthreads();
#pragma unroll
    for (int i = 0; i < 4; i++)
        dst[(size_t)(n0 + ty + i * 8) * 1024 + k0 + tx] = f2bf(tile[tx][ty + i * 8]);
}

// ------- merged transpose + cast for W1 [1024][4096] and W2 [4096][1024] -----------
__global__ __launch_bounds__(256)
void transpose_cast_w12(const float* __restrict__ W1, const float* __restrict__ W2,
                        u16* __restrict__ d1, u16* __restrict__ d2) {
    __shared__ float tile[32][33];
    const int zz = blockIdx.z;
    const float* src;
    u16* dst;
    int n0, k0, N, K;
    if (zz == 0) {  // W1: src [1024][4096] -> dst [4096][1024]
        src = W1; dst = d1; N = 4096; K = 1024;
        n0 = blockIdx.x * 32; k0 = blockIdx.y * 32;
    } else {        // W2: src [4096][1024] -> dst [1024][4096]
        src = W2; dst = d2; N = 1024; K = 4096;
        int idx = blockIdx.y * 128 + blockIdx.x;   // 0..4095
        n0 = (idx & 31) * 32; k0 = (idx >> 5) * 32;
    }
    int tx = threadIdx.x, ty = threadIdx.y;
#pragma unroll
    for (int i = 0; i < 4; i++)
        tile[ty + i * 8][tx] = src[(size_t)(k0 + ty + i * 8) * N + n0 + tx];
    __syncthreads();
#pragma unroll
    for (int i = 0; i < 4; i++)
        dst[(size_t)(n0 + ty + i * 8) * K + k0 + tx] = f2bf(tile[tx][ty + i * 8]);
}

// ---------------- LayerNorm (E=1024) + bf16 cast, f32 input ------------------------
__global__ __launch_bounds__(256)
void ln_kernel(const float* __restrict__ x, const float* __restrict__ g,
               const float* __restrict__ b, u16* __restrict__ out) {
    int row = blockIdx.x;
    int tid = threadIdx.x;
    float4 v = ((const float4*)(x + (size_t)row * E_DIM))[tid];
    float s = v.x + v.y + v.z + v.w;
    float sq = v.x * v.x + v.y * v.y + v.z * v.z + v.w * v.w;
#pragma unroll
    for (int off = 32; off; off >>= 1) {
        s += __shfl_xor(s, off);
        sq += __shfl_xor(sq, off);
    }
    __shared__ float sh[8];
    int w = tid >> 6, lane = tid & 63;
    if (lane == 0) { sh[w] = s; sh[4 + w] = sq; }
    __syncthreads();
    s = sh[0] + sh[1] + sh[2] + sh[3];
    sq = sh[4] + sh[5] + sh[6] + sh[7];
    float mu = s * (1.f / E_DIM);
    float var = sq * (1.f / E_DIM) - mu * mu;
    float rs = rsqrtf(var + 1e-5f);
    float4 gv = ((const float4*)g)[tid];
    float4 bv = ((const float4*)b)[tid];
    ushort4 o;
    o.x = f2bf((v.x - mu) * rs * gv.x + bv.x);
    o.y = f2bf((v.y - mu) * rs * gv.y + bv.y);
    o.z = f2bf((v.z - mu) * rs * gv.z + bv.z);
    o.w = f2bf((v.w - mu) * rs * gv.w + bv.w);
    ((ushort4*)(out + (size_t)row * E_DIM))[tid] = o;
}

// ---------------- LayerNorm (E=1024) + bf16 cast, bf16 input (x2 diet) -------------
__global__ __launch_bounds__(256)
void ln_kernel_bf(const u16* __restrict__ x, const float* __restrict__ g,
                  const float* __restrict__ b, u16* __restrict__ out) {
    int row = blockIdx.x;
    int tid = threadIdx.x;
    ushort4 uv = ((const ushort4*)(x + (size_t)row * E_DIM))[tid];
    float4 v;
    v.x = bf2f(uv.x); v.y = bf2f(uv.y); v.z = bf2f(uv.z); v.w = bf2f(uv.w);
    float s = v.x + v.y + v.z + v.w;
    float sq = v.x * v.x + v.y * v.y + v.z * v.z + v.w * v.w;
#pragma unroll
    for (int off = 32; off; off >>= 1) {
        s += __shfl_xor(s, off);
        sq += __shfl_xor(sq, off);
    }
    __shared__ float sh[8];
    int w = tid >> 6, lane = tid & 63;
    if (lane == 0) { sh[w] = s; sh[4 + w] = sq; }
    __syncthreads();
    s = sh[0] + sh[1] + sh[2] + sh[3];
    sq = sh[4] + sh[5] + sh[6] + sh[7];
    float mu = s * (1.f / E_DIM);
    float var = sq * (1.f / E_DIM) - mu * mu;
    float rs = rsqrtf(var + 1e-5f);
    float4 gv = ((const float4*)g)[tid];
    float4 bv = ((const float4*)b)[tid];
    ushort4 o;
    o.x = f2bf((v.x - mu) * rs * gv.x + bv.x);
    o.y = f2bf((v.y - mu) * rs * gv.y + bv.y);
    o.z = f2bf((v.z - mu) * rs * gv.z + bv.z);
    o.w = f2bf((v.w - mu) * rs * gv.w + bv.w);
    ((ushort4*)(out + (size_t)row * E_DIM))[tid] = o;
}

// ---------------- GEMM 256x128 tile, BK=64, 8 waves, 3-deep pipeline (R5) ----------
// MODE 0: bf16 out, QKV head-split; Q pre-scaled; V written DIRECTLY TRANSPOSED to
//         VT [B,H,64,T] via packed ushort4 (4 consecutive t per lane) -> outf=VT.
// MODE 1: bf16 out, +bias, ReLU
// MODE 2: bf16 out = f2bf(resid_f32 + acc + bias)   (x2 residual diet)
// MODE 4: f32 out = bf2f(resid_bf16) + acc + bias   (final W2, no split-K)
template <int MODE>
__global__ __launch_bounds__(512)
void gemm_bt128(const u16* __restrict__ A, const u16* __restrict__ BT,
                int M, int N, int K,
                const float* __restrict__ bias, const void* __restrict__ residv,
                float* __restrict__ outf, u16* __restrict__ outb) {
    __shared__ __align__(16) u16 As[3][256 * 64];
    __shared__ __align__(16) u16 Bs[3][128 * 64];

    const int gx = gridDim.x;
    const int nwg = gx * gridDim.y;
    const int l = blockIdx.y * gx + blockIdx.x;
    const int sw = (l & 7) * (nwg >> 3) + (l >> 3);
    const int tRow = (sw / gx) * 256, tCol = (sw % gx) * 128;

    const int tid = threadIdx.x, w = tid >> 6, lane = tid & 63;
    const int wr = w >> 1, wc = w & 1, lr = lane & 15, hg = lane >> 4;
    const int nk = K >> 6;

    f32x4 z = {0.f, 0.f, 0.f, 0.f};
    f32x4 acc[4][4];
#pragma unroll
    for (int m = 0; m < 4; m++)
#pragma unroll
        for (int n = 0; n < 4; n++) acc[m][n] = z;

    auto STAGE_A = [&](int kt, int c) {
#pragma unroll
        for (int i = 0; i < 4; i++) {
            int chunk = i * 512 + tid;
            int row = chunk >> 3, j = chunk & 7;
            int js = (j ^ (row & 7)) << 3;
            async_copy16(A + (size_t)(tRow + row) * K + (kt << 6) + js,
                         &As[c][(i * 512 + w * 64) * 8]);
        }
    };
    auto STAGE_B = [&](int kt, int c) {
#pragma unroll
        for (int i = 0; i < 2; i++) {
            int chunk = i * 512 + tid;
            int row = chunk >> 3, j = chunk & 7;
            int js = (j ^ (row & 7)) << 3;
            async_copy16(BT + (size_t)(tCol + row) * K + (kt << 6) + js,
                         &Bs[c][(i * 512 + w * 64) * 8]);
        }
    };

    STAGE_A(0, 0); STAGE_B(0, 0);
    STAGE_A(1, 1); STAGE_B(1, 1);
    asm volatile("s_waitcnt vmcnt(6)" ::: "memory");
    asm volatile("s_barrier" ::: "memory");

    for (int t = 0; t < nk; ++t) {
        const int bu = t % 3, nx = (t + 2) % 3;
        const u16* Ab = &As[bu][0];
        const u16* Bb = &Bs[bu][0];
        const bool more = (t + 2 < nk);

        // ---- phase 0 ----
        s8v af0[2][2], bf[4][2];
#pragma unroll
        for (int m = 0; m < 2; m++)
#pragma unroll
            for (int kk = 0; kk < 2; kk++) {
                int r = wr * 64 + m * 16 + lr;
                af0[m][kk] = *(const s8v*)&Ab[r * 64 + (((kk * 4 + hg) ^ (r & 7)) << 3)];
            }
#pragma unroll
        for (int n = 0; n < 4; n++)
#pragma unroll
            for (int kk = 0; kk < 2; kk++) {
                int r = wc * 64 + n * 16 + lr;
                bf[n][kk] = *(const s8v*)&Bb[r * 64 + (((kk * 4 + hg) ^ (r & 7)) << 3)];
            }
        if (more) STAGE_A(t + 2, nx);
        asm volatile("s_barrier" ::: "memory");
        __builtin_amdgcn_s_setprio(1);
#pragma unroll
        for (int m = 0; m < 2; m++)
#pragma unroll
            for (int n = 0; n < 4; n++)
#pragma unroll
                for (int kk = 0; kk < 2; kk++)
                    acc[m][n] = __builtin_amdgcn_mfma_f32_16x16x32_bf16(
                        af0[m][kk], bf[n][kk], acc[m][n], 0, 0, 0);
        __builtin_amdgcn_s_setprio(0);
        asm volatile("s_barrier" ::: "memory");

        // ---- phase 1 ----
        s8v af1[2][2];
#pragma unroll
        for (int m = 0; m < 2; m++)
#pragma unroll
            for (int kk = 0; kk < 2; kk++) {
                int r = wr * 64 + (m + 2) * 16 + lr;
                af1[m][kk] = *(const s8v*)&Ab[r * 64 + (((kk * 4 + hg) ^ (r & 7)) << 3)];
            }
        if (more) STAGE_B(t + 2, nx);
        asm volatile("s_barrier" ::: "memory");
        __builtin_amdgcn_s_setprio(1);
#pragma unroll
        for (int m = 0; m < 2; m++)
#pragma unroll
            for (int n = 0; n < 4; n++)
#pragma unroll
                for (int kk = 0; kk < 2; kk++)
                    acc[m + 2][n] = __builtin_amdgcn_mfma_f32_16x16x32_bf16(
                        af1[m][kk], bf[n][kk], acc[m + 2][n], 0, 0, 0);
        __builtin_amdgcn_s_setprio(0);
        if (more) asm volatile("s_waitcnt vmcnt(6)" ::: "memory");
        else      asm volatile("s_waitcnt vmcnt(0)" ::: "memory");
        asm volatile("s_barrier" ::: "memory");
    }

#pragma unroll
    for (int m = 0; m < 4; m++)
#pragma unroll
        for (int n = 0; n < 4; n++) {
            if (MODE == 0) {
                int col = tCol + wc * 64 + n * 16 + lr;
                int type = col >> 10, c2 = col & 1023;
                int h = c2 >> 6, d = c2 & 63;
                int row0 = tRow + wr * 64 + m * 16 + hg * 4;
                int bb = row0 >> 11, t0 = row0 & 2047;
                if (type == 2) {
                    // V direct-transposed: 4 consecutive t at fixed d -> ushort4
                    ushort4 pk;
                    pk.x = f2bf(acc[m][n][0]);
                    pk.y = f2bf(acc[m][n][1]);
                    pk.z = f2bf(acc[m][n][2]);
                    pk.w = f2bf(acc[m][n][3]);
                    u16* vt = (u16*)outf;
                    *(ushort4*)&vt[(((size_t)(bb * H_NUM + h) * 64 + d) << 11) + t0] = pk;
                } else {
#pragma unroll
                    for (int r = 0; r < 4; r++) {
                        float v = acc[m][n][r];
                        if (type == 0) v *= QSCALE;
                        outb[(size_t)type * 8388608 +
                             (((size_t)(bb * H_NUM + h) * T_SEQ + t0 + r) << 6) + d] = f2bf(v);
                    }
                }
            } else {
#pragma unroll
                for (int r = 0; r < 4; r++) {
                    int row = tRow + wr * 64 + m * 16 + hg * 4 + r;
                    int col = tCol + wc * 64 + n * 16 + lr;
                    float v = acc[m][n][r];
                    if (MODE == 1) {
                        v += bias[col];
                        v = fmaxf(v, 0.f);
                        outb[(size_t)row * N + col] = f2bf(v);
                    } else if (MODE == 2) {
                        const float* resid = (const float*)residv;
                        outb[(size_t)row * N + col] =
                            f2bf(resid[(size_t)row * N + col] + v + bias[col]);
                    } else {  // MODE 4
                        const u16* resid = (const u16*)residv;
                        outf[(size_t)row * N + col] =
                            bf2f(resid[(size_t)row * N + col]) + v + bias[col];
                    }
                }
            }
        }
}

// ---------------- GEMM 256x256 tile, BK=64, 8 waves (2Mx4N), deep-slack (R9) -------
// MODE 1: bf16 +bias ReLU (W1 only now).
template <int MODE>
__global__ __launch_bounds__(512)
void gemm_bt256(const u16* __restrict__ A, const u16* __restrict__ BT,
                int M, int N, int Kst, int klen,
                const float* __restrict__ bias, const float* __restrict__ resid,
                float* __restrict__ outf, u16* __restrict__ outb) {
    __shared__ __align__(16) u16 As[2][256 * 64];
    __shared__ __align__(16) u16 Bs[2][256 * 64];

    const int gx = gridDim.x;  // N/256
    const int nwg = gx * gridDim.y;
    const int l = blockIdx.y * gx + blockIdx.x;
    const int sw = (l & 7) * (nwg >> 3) + (l >> 3);
    const int tRow = (sw / gx) * 256, tCol = (sw % gx) * 256;
    const size_t koff = (size_t)blockIdx.z * klen;
    const u16* Az = A + koff;
    const u16* BTz = BT + koff;

    const int tid = threadIdx.x, w = tid >> 6, lane = tid & 63;
    const int wr = w >> 2, wc = w & 3, lr = lane & 15, hg = lane >> 4;
    const int nk = klen >> 6;

    f32x4 z = {0.f, 0.f, 0.f, 0.f};
    f32x4 acc[8][4];
#pragma unroll
    for (int m = 0; m < 8; m++)
#pragma unroll
        for (int n = 0; n < 4; n++) acc[m][n] = z;

    auto STAGE_A = [&](int kt, int c, int h) {
#pragma unroll
        for (int i = 0; i < 2; i++) {
            int chunk = h * 1024 + i * 512 + tid;
            int row = chunk >> 3, j = chunk & 7;
            int js = (j ^ (row & 7)) << 3;
            async_copy16(Az + (size_t)(tRow + row) * Kst + (kt << 6) + js,
                         &As[c][(h * 1024 + i * 512 + w * 64) * 8]);
        }
    };
    auto STAGE_B = [&](int kt, int c, int h) {
#pragma unroll
        for (int i = 0; i < 2; i++) {
            int chunk = h * 1024 + i * 512 + tid;
            int row = chunk >> 3, j = chunk & 7;
            int js = (j ^ (row & 7)) << 3;
            async_copy16(BTz + (size_t)(tCol + row) * Kst + (kt << 6) + js,
                         &Bs[c][(h * 1024 + i * 512 + w * 64) * 8]);
        }
    };

    STAGE_B(0, 0, 0); STAGE_B(0, 0, 1); STAGE_A(0, 0, 0); STAGE_A(0, 0, 1);
    STAGE_B(1, 1, 0); STAGE_B(1, 1, 1); STAGE_A(1, 1, 0); STAGE_A(1, 1, 1);
    asm volatile("s_waitcnt vmcnt(6)" ::: "memory");
    asm volatile("s_barrier" ::: "memory");

    for (int t = 0; t < nk; ++t) {
        const int cur = t & 1;
        const u16* Ab = &As[cur][0];
        const u16* Bb = &Bs[cur][0];
        const bool more = (t + 2 < nk);

        s8v bf[4][2];
#pragma unroll
        for (int p = 0; p < 4; p++) {
            s8v af[2][2];
#pragma unroll
            for (int mm = 0; mm < 2; mm++)
#pragma unroll
                for (int kk = 0; kk < 2; kk++) {
                    int r = (2 * p + mm) * 32 + wr * 16 + lr;
                    af[mm][kk] = *(const s8v*)&Ab[r * 64 + (((kk * 4 + hg) ^ (r & 7)) << 3)];
                }
            if (p == 0) {
#pragma unroll
                for (int n = 0; n < 4; n++)
#pragma unroll
                    for (int kk = 0; kk < 2; kk++) {
                        int r = n * 64 + wc * 16 + lr;
                        bf[n][kk] = *(const s8v*)&Bb[r * 64 + (((kk * 4 + hg) ^ (r & 7)) << 3)];
                    }
            }
            if (more) {
                if (p == 0) STAGE_B(t + 2, cur, 0);
                else if (p == 1) STAGE_B(t + 2, cur, 1);
                else if (p == 2) STAGE_A(t + 2, cur, 0);
                else STAGE_A(t + 2, cur, 1);
            }
            asm volatile("s_barrier" ::: "memory");
            __builtin_amdgcn_s_setprio(1);
#pragma unroll
            for (int mm = 0; mm < 2; mm++)
#pragma unroll
                for (int n = 0; n < 4; n++)
#pragma unroll
                    for (int kk = 0; kk < 2; kk++)
                        acc[2 * p + mm][n] = __builtin_amdgcn_mfma_f32_16x16x32_bf16(
                            af[mm][kk], bf[n][kk], acc[2 * p + mm][n], 0, 0, 0);
            __builtin_amdgcn_s_setprio(0);
            if (p == 3) {
                if (more) asm volatile("s_waitcnt vmcnt(6)" ::: "memory");
                else      asm volatile("s_waitcnt vmcnt(0)" ::: "memory");
            }
            asm volatile("s_barrier" ::: "memory");
        }
    }

#pragma unroll
    for (int m = 0; m < 8; m++)
#pragma unroll
        for (int n = 0; n < 4; n++)
#pragma unroll
            for (int r = 0; r < 4; r++) {
                int row = tRow + m * 32 + wr * 16 + hg * 4 + r;
                int col = tCol + n * 64 + wc * 16 + lr;
                float v = acc[m][n][r];
                v += bias[col];
                v = fmaxf(v, 0.f);
                outb[(size_t)row * N + col] = f2bf(v);
            }
}

// ---------------- causal flash attention, HS=64, 8 waves, paired q-tiles (R13) -----
__global__ __launch_bounds__(512)
void attn_kernel(const u16* __restrict__ Q, const u16* __restrict__ K,
                 const u16* __restrict__ VT, u16* __restrict__ O) {
    __shared__ u16 Ks[2][64 * 64];
    __shared__ u16 Vs[2][64 * 64];
    __shared__ u16 Pl[8][16 * 64];
    const int bh = blockIdx.y;
    const u16* Qh = Q + (size_t)bh * T_SEQ * HS;
    const u16* Kh = K + (size_t)bh * T_SEQ * HS;
    const u16* VTh = VT + (size_t)bh * T_SEQ * HS;
    const int tid = threadIdx.x, w = tid >> 6, lane = tid & 63;
    const int lr = lane & 15, hg = lane >> 4;
    const int swz = (lr & 7) << 3;
    const int bb = bh >> 4, hh = bh & 15;
    const f32x4 z = {0.f, 0.f, 0.f, 0.f};

    for (int half = 0; half < 2; ++half) {
        const int qt = half ? (15 - blockIdx.x) : blockIdx.x;
        const int qb = qt * 128;
        const int nt = 2 * qt + 2;

        s8v qf[2];
        {
            const int qrow = qb + w * 16 + lr;
            qf[0] = *(const s8v*)(Qh + (size_t)qrow * HS + hg * 8);
            qf[1] = *(const s8v*)(Qh + (size_t)qrow * HS + 32 + hg * 8);
        }
        f32x4 o[4] = {z, z, z, z};
        float m_run[4] = {0.f, 0.f, 0.f, 0.f};
        float l_part[4] = {0.f, 0.f, 0.f, 0.f};

        auto STAGE = [&](int t, int c) {
            int chunk = tid;
            int row = chunk >> 3, j = chunk & 7;
            int js = (j ^ (row & 7)) << 3;
            async_copy16(Kh + (size_t)t * (64 * HS) + row * HS + js, &Ks[c][w * 512]);
            async_copy16(VTh + (size_t)row * T_SEQ + t * 64 + js, &Vs[c][w * 512]);
        };

        int cur = 0;
        STAGE(0, 0);
        __syncthreads();

        for (int t = 0; t < nt; ++t) {
            if (t + 1 < nt) STAGE(t + 1, cur ^ 1);

            f32x4 s[4];
            __builtin_amdgcn_s_setprio(1);
#pragma unroll
            for (int n = 0; n < 4; n++) {
                f32x4 a = z;
#pragma unroll
                for (int kc = 0; kc < 2; kc++) {
                    s8v bfr = *(const s8v*)&Ks[cur][((n * 16 + lr) * 64 + kc * 32 + hg * 8) ^ swz];
                    a = __builtin_amdgcn_mfma_f32_16x16x32_bf16(qf[kc], bfr, a, 0, 0, 0);
                }
                s[n] = a;
            }
            __builtin_amdgcn_s_setprio(0);
            const bool diag = (t >= nt - 2);
            if (diag) {
#pragma unroll
                for (int n = 0; n < 4; n++)
#pragma unroll
                    for (int r = 0; r < 4; r++)
                        if ((t * 64 + n * 16 + lr) > (qb + w * 16 + hg * 4 + r))
                            s[n][r] = -1e30f;
            }
            float d0[4][4], p4[4][4];
#pragma unroll
            for (int n = 0; n < 4; n++)
#pragma unroll
                for (int r = 0; r < 4; r++) {
                    d0[n][r] = s[n][r] - m_run[r];
                    p4[n][r] = __builtin_amdgcn_exp2f(d0[n][r]);
                }
            float sm[4];
#pragma unroll
            for (int r = 0; r < 4; r++)
                sm[r] = (p4[0][r] + p4[1][r]) + (p4[2][r] + p4[3][r]);
            float smax = fmaxf(fmaxf(sm[0], sm[1]), fmaxf(sm[2], sm[3]));
            if (__any(!(smax <= 2048.f))) {
                float pm[4];
#pragma unroll
                for (int r = 0; r < 4; r++) {
                    float m0 = fmaxf(fmaxf(d0[0][r], d0[1][r]), fmaxf(d0[2][r], d0[3][r]));
                    m0 = fmaxf(m0, __shfl_xor(m0, 1));
                    m0 = fmaxf(m0, __shfl_xor(m0, 2));
                    m0 = fmaxf(m0, __shfl_xor(m0, 4));
                    m0 = fmaxf(m0, __shfl_xor(m0, 8));
                    pm[r] = fmaxf(m0, 0.f);
                }
#pragma unroll
                for (int r = 0; r < 4; r++) {
                    float al = __builtin_amdgcn_exp2f(-pm[r]);
                    m_run[r] += pm[r];
                    l_part[r] *= al;
                    o[0][r] *= al; o[1][r] *= al; o[2][r] *= al; o[3][r] *= al;
                }
#pragma unroll
                for (int n = 0; n < 4; n++)
#pragma unroll
                    for (int r = 0; r < 4; r++)
                        p4[n][r] = __builtin_amdgcn_exp2f(d0[n][r] - pm[r]);
#pragma unroll
                for (int r = 0; r < 4; r++)
                    sm[r] = (p4[0][r] + p4[1][r]) + (p4[2][r] + p4[3][r]);
            }
#pragma unroll
            for (int r = 0; r < 4; r++) l_part[r] += sm[r];
            u16* Pw = &Pl[w][0];
#pragma unroll
            for (int n = 0; n < 4; n++)
#pragma unroll
                for (int r = 0; r < 4; r++) {
                    int prow = hg * 4 + r;
                    Pw[(prow * 64 + n * 16 + lr) ^ ((prow & 7) << 3)] =
                        (u16)(__builtin_bit_cast(unsigned int, p4[n][r]) >> 16);
                }
            asm volatile("s_waitcnt lgkmcnt(0)" ::: "memory");
            __builtin_amdgcn_s_setprio(1);
#pragma unroll
            for (int n = 0; n < 4; n++) {
#pragma unroll
                for (int kc = 0; kc < 2; kc++) {
                    s8v pa = *(const s8v*)&Pw[(lr * 64 + kc * 32 + hg * 8) ^ swz];
                    s8v vb = *(const s8v*)&Vs[cur][((n * 16 + lr) * 64 + kc * 32 + hg * 8) ^ swz];
                    o[n] = __builtin_amdgcn_mfma_f32_16x16x32_bf16(pa, vb, o[n], 0, 0, 0);
                }
            }
            __builtin_amdgcn_s_setprio(0);
            __syncthreads();
            cur ^= 1;
        }
        float rl[4];
#pragma unroll
        for (int r = 0; r < 4; r++) {
            float lsum = l_part[r];
            lsum += __shfl_xor(lsum, 1);
            lsum += __shfl_xor(lsum, 2);
            lsum += __shfl_xor(lsum, 4);
            lsum += __shfl_xor(lsum, 8);
            rl[r] = 1.f / lsum;
        }
#pragma unroll
        for (int n = 0; n < 4; n++)
#pragma unroll
            for (int r = 0; r < 4; r++) {
                int trow = qb + w * 16 + hg * 4 + r;
                O[((size_t)(bb * T_SEQ + trow)) * E_DIM + hh * HS + n * 16 + lr] =
                    f2bf(o[n][r] * rl[r]);
            }
    }
}

// ---------------- launch ----------------
extern "C" void kernel_launch(void* const* d_in, const int* in_sizes, int n_in,
                              void* d_out, int out_size, void* d_ws, size_t ws_size,
                              hipStream_t stream) {
    (void)in_sizes; (void)n_in; (void)out_size; (void)ws_size;
    const float* x  = (const float*)d_in[0];
    const float* Wq = (const float*)d_in[1];
    const float* Wk = (const float*)d_in[2];
    const float* Wv = (const float*)d_in[3];
    const float* Wp = (const float*)d_in[4];
    const float* bp = (const float*)d_in[5];
    const float* W1 = (const float*)d_in[6];
    const float* b1 = (const float*)d_in[7];
    const float* W2 = (const float*)d_in[8];
    const float* b2 = (const float*)d_in[9];
    const float* g1  = (const float*)d_in[10];
    const float* be1 = (const float*)d_in[11];
    const float* g2  = (const float*)d_in[12];
    const float* be2 = (const float*)d_in[13];

    char* ws = (char*)d_ws;
    u16* wqkv_t  = (u16*)(ws);                          // [3072][1024] bf16, 6 MB
    u16* wp_t    = (u16*)(ws + 6291456);                // [1024][1024], 2 MB
    u16* w1_t    = (u16*)(ws + 8388608);                // [4096][1024], 8 MB
    u16* w2_t    = (u16*)(ws + 16777216);               // [1024][4096], 8 MB
    u16* h_bf    = (u16*)(ws + 25165824);               // [8192][1024], 16 MB (h1 / h2)
    u16* q_bf    = (u16*)(ws + 41943040);               // Q,K [B,H,T,64]; VT [B,H,64,T]; attn
    u16* vt_bf   = q_bf + 2 * 8388608;                  // VT written by QKV epilogue
    u16* attn_bf = q_bf + 3 * 8388608;
    u16* ff1     = q_bf;                                 // reuse 64 MB region (W1 out)
    u16* x2b     = (u16*)(ws + 109051904);              // [8192][1024] bf16, 16 MB

    dim3 b32(32, 8);
    transpose_cast4<<<dim3(32, 32, 4), b32, 0, stream>>>(Wq, Wk, Wv, Wp, wqkv_t, wp_t);
    transpose_cast_w12<<<dim3(128, 32, 2), b32, 0, stream>>>(W1, W2, w1_t, w2_t);

    ln_kernel<<<M_ROWS, 256, 0, stream>>>(x, g1, be1, h_bf);
    // QKV: Q,K head-split + V direct-transposed to vt_bf (outf carries VT base)
    gemm_bt128<0><<<dim3(24, 32), 512, 0, stream>>>(h_bf, wqkv_t, M_ROWS, 3072, 1024,
                                                    nullptr, nullptr, (float*)vt_bf, q_bf);
    attn_kernel<<<dim3(8, 64), 512, 0, stream>>>(q_bf, q_bf + 8388608, vt_bf, attn_bf);
    gemm_bt128<2><<<dim3(8, 32), 512, 0, stream>>>(attn_bf, wp_t, M_ROWS, 1024, 1024,
                                                   bp, x, nullptr, x2b);
    ln_kernel_bf<<<M_ROWS, 256, 0, stream>>>(x2b, g2, be2, h_bf);
    gemm_bt256<1><<<dim3(16, 32), 512, 0, stream>>>(h_bf, w1_t, M_ROWS, 4096, 1024, 1024,
                                                    b1, nullptr, nullptr, ff1);
    // W2: plain bt128, fused bf16-resid + bias, f32 out (split-K retired: 88.4 < 91.3)
    gemm_bt128<4><<<dim3(8, 32), 512, 0, stream>>>(ff1, w2_t, M_ROWS, 1024, 4096,
                                                   b2, x2b, (float*)d_out, nullptr);
}

// Round 16
// 335.745 us; speedup vs baseline: 1.1942x; 1.0094x over previous
//
#include <hip/hip_runtime.h>
#include <stdint.h>

typedef unsigned short u16;
typedef short s8v __attribute__((ext_vector_type(8)));
typedef float f32x4 __attribute__((ext_vector_type(4)));

#define B_SZ 4
#define T_SEQ 2048
#define E_DIM 1024
#define H_NUM 16
#define HS 64
#define FF_DIM 4096
#define M_ROWS 8192  // B*T
// Q pre-scale: E^-0.5 * log2(e) -> QK^T scores arrive in log2 domain
#define QSCALE 0.0450842200f

__device__ __forceinline__ u16 f2bf(float f) {
    unsigned int u = __builtin_bit_cast(unsigned int, f);
    u += 0x7fffu + ((u >> 16) & 1u);
    return (u16)(u >> 16);
}

__device__ __forceinline__ float bf2f(u16 u) {
    unsigned int v = ((unsigned int)u) << 16;
    return __builtin_bit_cast(float, v);
}

__device__ __forceinline__ void async_copy16(const void* g, void* l) {
    __builtin_amdgcn_global_load_lds(
        (const __attribute__((address_space(1))) unsigned int*)g,
        (__attribute__((address_space(3))) unsigned int*)l, 16, 0, 0);
}

// ------- batched transpose + cast for the four 1024x1024 weights (Wq,Wk,Wv,Wp) -----
__global__ __launch_bounds__(256)
void transpose_cast4(const float* __restrict__ s0, const float* __restrict__ s1,
                     const float* __restrict__ s2, const float* __restrict__ s3,
                     u16* __restrict__ dqkv, u16* __restrict__ dp) {
    __shared__ float tile[32][33];
    const int zz = blockIdx.z;
    const float* src = (zz == 0) ? s0 : (zz == 1) ? s1 : (zz == 2) ? s2 : s3;
    u16* dst = (zz < 3) ? dqkv + (size_t)zz * 1048576 : dp;
    int n0 = blockIdx.x * 32, k0 = blockIdx.y * 32;
    int tx = threadIdx.x, ty = threadIdx.y;
#pragma unroll
    for (int i = 0; i < 4; i++)
        tile[ty + i * 8][tx] = src[(size_t)(k0 + ty + i * 8) * 1024 + n0 + tx];
    __syncthreads();
#pragma unroll
    for (int i = 0; i < 4; i++)
        dst[(size_t)(n0 + ty + i * 8) * 1024 + k0 + tx] = f2bf(tile[tx][ty + i * 8]);
}

// ------- merged transpose + cast for W1 [1024][4096] and W2 [4096][1024] -----------
__global__ __launch_bounds__(256)
void transpose_cast_w12(const float* __restrict__ W1, const float* __restrict__ W2,
                        u16* __restrict__ d1, u16* __restrict__ d2) {
    __shared__ float tile[32][33];
    const int zz = blockIdx.z;
    const float* src;
    u16* dst;
    int n0, k0, N, K;
    if (zz == 0) {  // W1: src [1024][4096] -> dst [4096][1024]
        src = W1; dst = d1; N = 4096; K = 1024;
        n0 = blockIdx.x * 32; k0 = blockIdx.y * 32;
    } else {        // W2: src [4096][1024] -> dst [1024][4096]
        src = W2; dst = d2; N = 1024; K = 4096;
        int idx = blockIdx.y * 128 + blockIdx.x;   // 0..4095
        n0 = (idx & 31) * 32; k0 = (idx >> 5) * 32;
    }
    int tx = threadIdx.x, ty = threadIdx.y;
#pragma unroll
    for (int i = 0; i < 4; i++)
        tile[ty + i * 8][tx] = src[(size_t)(k0 + ty + i * 8) * N + n0 + tx];
    __syncthreads();
#pragma unroll
    for (int i = 0; i < 4; i++)
        dst[(size_t)(n0 + ty + i * 8) * K + k0 + tx] = f2bf(tile[tx][ty + i * 8]);
}

// ---------------- LayerNorm (E=1024) + bf16 cast, f32 input ------------------------
__global__ __launch_bounds__(256)
void ln_kernel(const float* __restrict__ x, const float* __restrict__ g,
               const float* __restrict__ b, u16* __restrict__ out) {
    int row = blockIdx.x;
    int tid = threadIdx.x;
    float4 v = ((const float4*)(x + (size_t)row * E_DIM))[tid];
    float s = v.x + v.y + v.z + v.w;
    float sq = v.x * v.x + v.y * v.y + v.z * v.z + v.w * v.w;
#pragma unroll
    for (int off = 32; off; off >>= 1) {
        s += __shfl_xor(s, off);
        sq += __shfl_xor(sq, off);
    }
    __shared__ float sh[8];
    int w = tid >> 6, lane = tid & 63;
    if (lane == 0) { sh[w] = s; sh[4 + w] = sq; }
    __syncthreads();
    s = sh[0] + sh[1] + sh[2] + sh[3];
    sq = sh[4] + sh[5] + sh[6] + sh[7];
    float mu = s * (1.f / E_DIM);
    float var = sq * (1.f / E_DIM) - mu * mu;
    float rs = rsqrtf(var + 1e-5f);
    float4 gv = ((const float4*)g)[tid];
    float4 bv = ((const float4*)b)[tid];
    ushort4 o;
    o.x = f2bf((v.x - mu) * rs * gv.x + bv.x);
    o.y = f2bf((v.y - mu) * rs * gv.y + bv.y);
    o.z = f2bf((v.z - mu) * rs * gv.z + bv.z);
    o.w = f2bf((v.w - mu) * rs * gv.w + bv.w);
    ((ushort4*)(out + (size_t)row * E_DIM))[tid] = o;
}

// ---------------- LayerNorm (E=1024) + bf16 cast, bf16 input (x2 diet) -------------
__global__ __launch_bounds__(256)
void ln_kernel_bf(const u16* __restrict__ x, const float* __restrict__ g,
                  const float* __restrict__ b, u16* __restrict__ out) {
    int row = blockIdx.x;
    int tid = threadIdx.x;
    ushort4 uv = ((const ushort4*)(x + (size_t)row * E_DIM))[tid];
    float4 v;
    v.x = bf2f(uv.x); v.y = bf2f(uv.y); v.z = bf2f(uv.z); v.w = bf2f(uv.w);
    float s = v.x + v.y + v.z + v.w;
    float sq = v.x * v.x + v.y * v.y + v.z * v.z + v.w * v.w;
#pragma unroll
    for (int off = 32; off; off >>= 1) {
        s += __shfl_xor(s, off);
        sq += __shfl_xor(sq, off);
    }
    __shared__ float sh[8];
    int w = tid >> 6, lane = tid & 63;
    if (lane == 0) { sh[w] = s; sh[4 + w] = sq; }
    __syncthreads();
    s = sh[0] + sh[1] + sh[2] + sh[3];
    sq = sh[4] + sh[5] + sh[6] + sh[7];
    float mu = s * (1.f / E_DIM);
    float var = sq * (1.f / E_DIM) - mu * mu;
    float rs = rsqrtf(var + 1e-5f);
    float4 gv = ((const float4*)g)[tid];
    float4 bv = ((const float4*)b)[tid];
    ushort4 o;
    o.x = f2bf((v.x - mu) * rs * gv.x + bv.x);
    o.y = f2bf((v.y - mu) * rs * gv.y + bv.y);
    o.z = f2bf((v.z - mu) * rs * gv.z + bv.z);
    o.w = f2bf((v.w - mu) * rs * gv.w + bv.w);
    ((ushort4*)(out + (size_t)row * E_DIM))[tid] = o;
}

// ---------------- GEMM 256x128 tile, BK=64, 8 waves, 3-deep pipeline (R5) ----------
// MODE 0: bf16 out, QKV head-split; Q pre-scaled; V written DIRECTLY TRANSPOSED to
//         VT [B,H,64,T] via packed ushort4 (4 consecutive t per lane) -> outf=VT.
// MODE 1: bf16 out, +bias, ReLU
// MODE 2: bf16 out = f2bf(resid_f32 + acc + bias)   (x2 residual diet)
// MODE 4: f32 out = bf2f(resid_bf16) + acc + bias   (final W2)
template <int MODE>
__global__ __launch_bounds__(512)
void gemm_bt128(const u16* __restrict__ A, const u16* __restrict__ BT,
                int M, int N, int K,
                const float* __restrict__ bias, const void* __restrict__ residv,
                float* __restrict__ outf, u16* __restrict__ outb) {
    __shared__ __align__(16) u16 As[3][256 * 64];
    __shared__ __align__(16) u16 Bs[3][128 * 64];

    const int gx = gridDim.x;
    const int nwg = gx * gridDim.y;
    const int l = blockIdx.y * gx + blockIdx.x;
    const int sw = (l & 7) * (nwg >> 3) + (l >> 3);
    const int tRow = (sw / gx) * 256, tCol = (sw % gx) * 128;

    const int tid = threadIdx.x, w = tid >> 6, lane = tid & 63;
    const int wr = w >> 1, wc = w & 1, lr = lane & 15, hg = lane >> 4;
    const int nk = K >> 6;

    f32x4 z = {0.f, 0.f, 0.f, 0.f};
    f32x4 acc[4][4];
#pragma unroll
    for (int m = 0; m < 4; m++)
#pragma unroll
        for (int n = 0; n < 4; n++) acc[m][n] = z;

    auto STAGE_A = [&](int kt, int c) {
#pragma unroll
        for (int i = 0; i < 4; i++) {
            int chunk = i * 512 + tid;
            int row = chunk >> 3, j = chunk & 7;
            int js = (j ^ (row & 7)) << 3;
            async_copy16(A + (size_t)(tRow + row) * K + (kt << 6) + js,
                         &As[c][(i * 512 + w * 64) * 8]);
        }
    };
    auto STAGE_B = [&](int kt, int c) {
#pragma unroll
        for (int i = 0; i < 2; i++) {
            int chunk = i * 512 + tid;
            int row = chunk >> 3, j = chunk & 7;
            int js = (j ^ (row & 7)) << 3;
            async_copy16(BT + (size_t)(tCol + row) * K + (kt << 6) + js,
                         &Bs[c][(i * 512 + w * 64) * 8]);
        }
    };

    STAGE_A(0, 0); STAGE_B(0, 0);
    STAGE_A(1, 1); STAGE_B(1, 1);
    asm volatile("s_waitcnt vmcnt(6)" ::: "memory");
    asm volatile("s_barrier" ::: "memory");

    for (int t = 0; t < nk; ++t) {
        const int bu = t % 3, nx = (t + 2) % 3;
        const u16* Ab = &As[bu][0];
        const u16* Bb = &Bs[bu][0];
        const bool more = (t + 2 < nk);

        // ---- phase 0 ----
        s8v af0[2][2], bf[4][2];
#pragma unroll
        for (int m = 0; m < 2; m++)
#pragma unroll
            for (int kk = 0; kk < 2; kk++) {
                int r = wr * 64 + m * 16 + lr;
                af0[m][kk] = *(const s8v*)&Ab[r * 64 + (((kk * 4 + hg) ^ (r & 7)) << 3)];
            }
#pragma unroll
        for (int n = 0; n < 4; n++)
#pragma unroll
            for (int kk = 0; kk < 2; kk++) {
                int r = wc * 64 + n * 16 + lr;
                bf[n][kk] = *(const s8v*)&Bb[r * 64 + (((kk * 4 + hg) ^ (r & 7)) << 3)];
            }
        if (more) STAGE_A(t + 2, nx);
        asm volatile("s_barrier" ::: "memory");
        __builtin_amdgcn_s_setprio(1);
#pragma unroll
        for (int m = 0; m < 2; m++)
#pragma unroll
            for (int n = 0; n < 4; n++)
#pragma unroll
                for (int kk = 0; kk < 2; kk++)
                    acc[m][n] = __builtin_amdgcn_mfma_f32_16x16x32_bf16(
                        af0[m][kk], bf[n][kk], acc[m][n], 0, 0, 0);
        __builtin_amdgcn_s_setprio(0);
        asm volatile("s_barrier" ::: "memory");

        // ---- phase 1 ----
        s8v af1[2][2];
#pragma unroll
        for (int m = 0; m < 2; m++)
#pragma unroll
            for (int kk = 0; kk < 2; kk++) {
                int r = wr * 64 + (m + 2) * 16 + lr;
                af1[m][kk] = *(const s8v*)&Ab[r * 64 + (((kk * 4 + hg) ^ (r & 7)) << 3)];
            }
        if (more) STAGE_B(t + 2, nx);
        asm volatile("s_barrier" ::: "memory");
        __builtin_amdgcn_s_setprio(1);
#pragma unroll
        for (int m = 0; m < 2; m++)
#pragma unroll
            for (int n = 0; n < 4; n++)
#pragma unroll
                for (int kk = 0; kk < 2; kk++)
                    acc[m + 2][n] = __builtin_amdgcn_mfma_f32_16x16x32_bf16(
                        af1[m][kk], bf[n][kk], acc[m + 2][n], 0, 0, 0);
        __builtin_amdgcn_s_setprio(0);
        if (more) asm volatile("s_waitcnt vmcnt(6)" ::: "memory");
        else      asm volatile("s_waitcnt vmcnt(0)" ::: "memory");
        asm volatile("s_barrier" ::: "memory");
    }

#pragma unroll
    for (int m = 0; m < 4; m++)
#pragma unroll
        for (int n = 0; n < 4; n++) {
            if (MODE == 0) {
                int col = tCol + wc * 64 + n * 16 + lr;
                int type = col >> 10, c2 = col & 1023;
                int h = c2 >> 6, d = c2 & 63;
                int row0 = tRow + wr * 64 + m * 16 + hg * 4;
                int bb = row0 >> 11, t0 = row0 & 2047;
                if (type == 2) {
                    ushort4 pk;
                    pk.x = f2bf(acc[m][n][0]);
                    pk.y = f2bf(acc[m][n][1]);
                    pk.z = f2bf(acc[m][n][2]);
                    pk.w = f2bf(acc[m][n][3]);
                    u16* vt = (u16*)outf;
                    *(ushort4*)&vt[(((size_t)(bb * H_NUM + h) * 64 + d) << 11) + t0] = pk;
                } else {
#pragma unroll
                    for (int r = 0; r < 4; r++) {
                        float v = acc[m][n][r];
                        if (type == 0) v *= QSCALE;
                        outb[(size_t)type * 8388608 +
                             (((size_t)(bb * H_NUM + h) * T_SEQ + t0 + r) << 6) + d] = f2bf(v);
                    }
                }
            } else {
#pragma unroll
                for (int r = 0; r < 4; r++) {
                    int row = tRow + wr * 64 + m * 16 + hg * 4 + r;
                    int col = tCol + wc * 64 + n * 16 + lr;
                    float v = acc[m][n][r];
                    if (MODE == 1) {
                        v += bias[col];
                        v = fmaxf(v, 0.f);
                        outb[(size_t)row * N + col] = f2bf(v);
                    } else if (MODE == 2) {
                        const float* resid = (const float*)residv;
                        outb[(size_t)row * N + col] =
                            f2bf(resid[(size_t)row * N + col] + v + bias[col]);
                    } else {  // MODE 4
                        const u16* resid = (const u16*)residv;
                        outf[(size_t)row * N + col] =
                            bf2f(resid[(size_t)row * N + col]) + v + bias[col];
                    }
                }
            }
        }
}

// ---------------- GEMM 256x256 tile, BK=64, 8 waves (2Mx4N), deep-slack (R9) -------
// MODE 1: bf16 +bias ReLU (W1 only).
template <int MODE>
__global__ __launch_bounds__(512)
void gemm_bt256(const u16* __restrict__ A, const u16* __restrict__ BT,
                int M, int N, int Kst, int klen,
                const float* __restrict__ bias, const float* __restrict__ resid,
                float* __restrict__ outf, u16* __restrict__ outb) {
    __shared__ __align__(16) u16 As[2][256 * 64];
    __shared__ __align__(16) u16 Bs[2][256 * 64];

    const int gx = gridDim.x;  // N/256
    const int nwg = gx * gridDim.y;
    const int l = blockIdx.y * gx + blockIdx.x;
    const int sw = (l & 7) * (nwg >> 3) + (l >> 3);
    const int tRow = (sw / gx) * 256, tCol = (sw % gx) * 256;
    const size_t koff = (size_t)blockIdx.z * klen;
    const u16* Az = A + koff;
    const u16* BTz = BT + koff;

    const int tid = threadIdx.x, w = tid >> 6, lane = tid & 63;
    const int wr = w >> 2, wc = w & 3, lr = lane & 15, hg = lane >> 4;
    const int nk = klen >> 6;

    f32x4 z = {0.f, 0.f, 0.f, 0.f};
    f32x4 acc[8][4];
#pragma unroll
    for (int m = 0; m < 8; m++)
#pragma unroll
        for (int n = 0; n < 4; n++) acc[m][n] = z;

    auto STAGE_A = [&](int kt, int c, int h) {
#pragma unroll
        for (int i = 0; i < 2; i++) {
            int chunk = h * 1024 + i * 512 + tid;
            int row = chunk >> 3, j = chunk & 7;
            int js = (j ^ (row & 7)) << 3;
            async_copy16(Az + (size_t)(tRow + row) * Kst + (kt << 6) + js,
                         &As[c][(h * 1024 + i * 512 + w * 64) * 8]);
        }
    };
    auto STAGE_B = [&](int kt, int c, int h) {
#pragma unroll
        for (int i = 0; i < 2; i++) {
            int chunk = h * 1024 + i * 512 + tid;
            int row = chunk >> 3, j = chunk & 7;
            int js = (j ^ (row & 7)) << 3;
            async_copy16(BTz + (size_t)(tCol + row) * Kst + (kt << 6) + js,
                         &Bs[c][(h * 1024 + i * 512 + w * 64) * 8]);
        }
    };

    STAGE_B(0, 0, 0); STAGE_B(0, 0, 1); STAGE_A(0, 0, 0); STAGE_A(0, 0, 1);
    STAGE_B(1, 1, 0); STAGE_B(1, 1, 1); STAGE_A(1, 1, 0); STAGE_A(1, 1, 1);
    asm volatile("s_waitcnt vmcnt(6)" ::: "memory");
    asm volatile("s_barrier" ::: "memory");

    for (int t = 0; t < nk; ++t) {
        const int cur = t & 1;
        const u16* Ab = &As[cur][0];
        const u16* Bb = &Bs[cur][0];
        const bool more = (t + 2 < nk);

        s8v bf[4][2];
#pragma unroll
        for (int p = 0; p < 4; p++) {
            s8v af[2][2];
#pragma unroll
            for (int mm = 0; mm < 2; mm++)
#pragma unroll
                for (int kk = 0; kk < 2; kk++) {
                    int r = (2 * p + mm) * 32 + wr * 16 + lr;
                    af[mm][kk] = *(const s8v*)&Ab[r * 64 + (((kk * 4 + hg) ^ (r & 7)) << 3)];
                }
            if (p == 0) {
#pragma unroll
                for (int n = 0; n < 4; n++)
#pragma unroll
                    for (int kk = 0; kk < 2; kk++) {
                        int r = n * 64 + wc * 16 + lr;
                        bf[n][kk] = *(const s8v*)&Bb[r * 64 + (((kk * 4 + hg) ^ (r & 7)) << 3)];
                    }
            }
            if (more) {
                if (p == 0) STAGE_B(t + 2, cur, 0);
                else if (p == 1) STAGE_B(t + 2, cur, 1);
                else if (p == 2) STAGE_A(t + 2, cur, 0);
                else STAGE_A(t + 2, cur, 1);
            }
            asm volatile("s_barrier" ::: "memory");
            __builtin_amdgcn_s_setprio(1);
#pragma unroll
            for (int mm = 0; mm < 2; mm++)
#pragma unroll
                for (int n = 0; n < 4; n++)
#pragma unroll
                    for (int kk = 0; kk < 2; kk++)
                        acc[2 * p + mm][n] = __builtin_amdgcn_mfma_f32_16x16x32_bf16(
                            af[mm][kk], bf[n][kk], acc[2 * p + mm][n], 0, 0, 0);
            __builtin_amdgcn_s_setprio(0);
            if (p == 3) {
                if (more) asm volatile("s_waitcnt vmcnt(6)" ::: "memory");
                else      asm volatile("s_waitcnt vmcnt(0)" ::: "memory");
            }
            asm volatile("s_barrier" ::: "memory");
        }
    }

#pragma unroll
    for (int m = 0; m < 8; m++)
#pragma unroll
        for (int n = 0; n < 4; n++)
#pragma unroll
            for (int r = 0; r < 4; r++) {
                int row = tRow + m * 32 + wr * 16 + hg * 4 + r;
                int col = tCol + n * 64 + wc * 16 + lr;
                float v = acc[m][n][r];
                v += bias[col];
                v = fmaxf(v, 0.f);
                outb[(size_t)row * N + col] = f2bf(v);
            }
}

// ---------------- causal flash attention, HS=64, 8 waves, paired q-tiles -----------
// NEW: grid axes swapped to (64 bh, 8 pair) so the 8 blocks sharing one bh's K/V
// get consecutive-ids with id%8 = bh%8 -> co-located on ONE XCD -> K/V L2 reuse.
__global__ __launch_bounds__(512)
void attn_kernel(const u16* __restrict__ Q, const u16* __restrict__ K,
                 const u16* __restrict__ VT, u16* __restrict__ O) {
    __shared__ u16 Ks[2][64 * 64];
    __shared__ u16 Vs[2][64 * 64];
    __shared__ u16 Pl[8][16 * 64];
    const int bh = blockIdx.x;        // swapped: bh on x
    const int pr = blockIdx.y;        // pair index on y
    const u16* Qh = Q + (size_t)bh * T_SEQ * HS;
    const u16* Kh = K + (size_t)bh * T_SEQ * HS;
    const u16* VTh = VT + (size_t)bh * T_SEQ * HS;
    const int tid = threadIdx.x, w = tid >> 6, lane = tid & 63;
    const int lr = lane & 15, hg = lane >> 4;
    const int swz = (lr & 7) << 3;
    const int bb = bh >> 4, hh = bh & 15;
    const f32x4 z = {0.f, 0.f, 0.f, 0.f};

    for (int half = 0; half < 2; ++half) {
        const int qt = half ? (15 - pr) : pr;
        const int qb = qt * 128;
        const int nt = 2 * qt + 2;

        s8v qf[2];
        {
            const int qrow = qb + w * 16 + lr;
            qf[0] = *(const s8v*)(Qh + (size_t)qrow * HS + hg * 8);
            qf[1] = *(const s8v*)(Qh + (size_t)qrow * HS + 32 + hg * 8);
        }
        f32x4 o[4] = {z, z, z, z};
        float m_run[4] = {0.f, 0.f, 0.f, 0.f};
        float l_part[4] = {0.f, 0.f, 0.f, 0.f};

        auto STAGE = [&](int t, int c) {
            int chunk = tid;
            int row = chunk >> 3, j = chunk & 7;
            int js = (j ^ (row & 7)) << 3;
            async_copy16(Kh + (size_t)t * (64 * HS) + row * HS + js, &Ks[c][w * 512]);
            async_copy16(VTh + (size_t)row * T_SEQ + t * 64 + js, &Vs[c][w * 512]);
        };

        int cur = 0;
        STAGE(0, 0);
        __syncthreads();

        for (int t = 0; t < nt; ++t) {
            if (t + 1 < nt) STAGE(t + 1, cur ^ 1);

            f32x4 s[4];
            __builtin_amdgcn_s_setprio(1);
#pragma unroll
            for (int n = 0; n < 4; n++) {
                f32x4 a = z;
#pragma unroll
                for (int kc = 0; kc < 2; kc++) {
                    s8v bfr = *(const s8v*)&Ks[cur][((n * 16 + lr) * 64 + kc * 32 + hg * 8) ^ swz];
                    a = __builtin_amdgcn_mfma_f32_16x16x32_bf16(qf[kc], bfr, a, 0, 0, 0);
                }
                s[n] = a;
            }
            __builtin_amdgcn_s_setprio(0);
            const bool diag = (t >= nt - 2);
            if (diag) {
#pragma unroll
                for (int n = 0; n < 4; n++)
#pragma unroll
                    for (int r = 0; r < 4; r++)
                        if ((t * 64 + n * 16 + lr) > (qb + w * 16 + hg * 4 + r))
                            s[n][r] = -1e30f;
            }
            float d0[4][4], p4[4][4];
#pragma unroll
            for (int n = 0; n < 4; n++)
#pragma unroll
                for (int r = 0; r < 4; r++) {
                    d0[n][r] = s[n][r] - m_run[r];
                    p4[n][r] = __builtin_amdgcn_exp2f(d0[n][r]);
                }
            float sm[4];
#pragma unroll
            for (int r = 0; r < 4; r++)
                sm[r] = (p4[0][r] + p4[1][r]) + (p4[2][r] + p4[3][r]);
            float smax = fmaxf(fmaxf(sm[0], sm[1]), fmaxf(sm[2], sm[3]));
            if (__any(!(smax <= 2048.f))) {
                float pm[4];
#pragma unroll
                for (int r = 0; r < 4; r++) {
                    float m0 = fmaxf(fmaxf(d0[0][r], d0[1][r]), fmaxf(d0[2][r], d0[3][r]));
                    m0 = fmaxf(m0, __shfl_xor(m0, 1));
                    m0 = fmaxf(m0, __shfl_xor(m0, 2));
                    m0 = fmaxf(m0, __shfl_xor(m0, 4));
                    m0 = fmaxf(m0, __shfl_xor(m0, 8));
                    pm[r] = fmaxf(m0, 0.f);
                }
#pragma unroll
                for (int r = 0; r < 4; r++) {
                    float al = __builtin_amdgcn_exp2f(-pm[r]);
                    m_run[r] += pm[r];
                    l_part[r] *= al;
                    o[0][r] *= al; o[1][r] *= al; o[2][r] *= al; o[3][r] *= al;
                }
#pragma unroll
                for (int n = 0; n < 4; n++)
#pragma unroll
                    for (int r = 0; r < 4; r++)
                        p4[n][r] = __builtin_amdgcn_exp2f(d0[n][r] - pm[r]);
#pragma unroll
                for (int r = 0; r < 4; r++)
                    sm[r] = (p4[0][r] + p4[1][r]) + (p4[2][r] + p4[3][r]);
            }
#pragma unroll
            for (int r = 0; r < 4; r++) l_part[r] += sm[r];
            u16* Pw = &Pl[w][0];
#pragma unroll
            for (int n = 0; n < 4; n++)
#pragma unroll
                for (int r = 0; r < 4; r++) {
                    int prow = hg * 4 + r;
                    Pw[(prow * 64 + n * 16 + lr) ^ ((prow & 7) << 3)] =
                        (u16)(__builtin_bit_cast(unsigned int, p4[n][r]) >> 16);
                }
            asm volatile("s_waitcnt lgkmcnt(0)" ::: "memory");
            __builtin_amdgcn_s_setprio(1);
#pragma unroll
            for (int n = 0; n < 4; n++) {
#pragma unroll
                for (int kc = 0; kc < 2; kc++) {
                    s8v pa = *(const s8v*)&Pw[(lr * 64 + kc * 32 + hg * 8) ^ swz];
                    s8v vb = *(const s8v*)&Vs[cur][((n * 16 + lr) * 64 + kc * 32 + hg * 8) ^ swz];
                    o[n] = __builtin_amdgcn_mfma_f32_16x16x32_bf16(pa, vb, o[n], 0, 0, 0);
                }
            }
            __builtin_amdgcn_s_setprio(0);
            __syncthreads();
            cur ^= 1;
        }
        float rl[4];
#pragma unroll
        for (int r = 0; r < 4; r++) {
            float lsum = l_part[r];
            lsum += __shfl_xor(lsum, 1);
            lsum += __shfl_xor(lsum, 2);
            lsum += __shfl_xor(lsum, 4);
            lsum += __shfl_xor(lsum, 8);
            rl[r] = 1.f / lsum;
        }
#pragma unroll
        for (int n = 0; n < 4; n++)
#pragma unroll
            for (int r = 0; r < 4; r++) {
                int trow = qb + w * 16 + hg * 4 + r;
                O[((size_t)(bb * T_SEQ + trow)) * E_DIM + hh * HS + n * 16 + lr] =
                    f2bf(o[n][r] * rl[r]);
            }
    }
}

// ---------------- launch ----------------
extern "C" void kernel_launch(void* const* d_in, const int* in_sizes, int n_in,
                              void* d_out, int out_size, void* d_ws, size_t ws_size,
                              hipStream_t stream) {
    (void)in_sizes; (void)n_in; (void)out_size; (void)ws_size;
    const float* x  = (const float*)d_in[0];
    const float* Wq = (const float*)d_in[1];
    const float* Wk = (const float*)d_in[2];
    const float* Wv = (const float*)d_in[3];
    const float* Wp = (const float*)d_in[4];
    const float* bp = (const float*)d_in[5];
    const float* W1 = (const float*)d_in[6];
    const float* b1 = (const float*)d_in[7];
    const float* W2 = (const float*)d_in[8];
    const float* b2 = (const float*)d_in[9];
    const float* g1  = (const float*)d_in[10];
    const float* be1 = (const float*)d_in[11];
    const float* g2  = (const float*)d_in[12];
    const float* be2 = (const float*)d_in[13];

    char* ws = (char*)d_ws;
    u16* wqkv_t  = (u16*)(ws);                          // [3072][1024] bf16, 6 MB
    u16* wp_t    = (u16*)(ws + 6291456);                // [1024][1024], 2 MB
    u16* w1_t    = (u16*)(ws + 8388608);                // [4096][1024], 8 MB
    u16* w2_t    = (u16*)(ws + 16777216);               // [1024][4096], 8 MB
    u16* h_bf    = (u16*)(ws + 25165824);               // [8192][1024], 16 MB (h1 / h2)
    u16* q_bf    = (u16*)(ws + 41943040);               // Q,K [B,H,T,64]; VT [B,H,64,T]; attn
    u16* vt_bf   = q_bf + 2 * 8388608;                  // VT written by QKV epilogue
    u16* attn_bf = q_bf + 3 * 8388608;
    u16* ff1     = q_bf;                                 // reuse 64 MB region (W1 out)
    u16* x2b     = (u16*)(ws + 109051904);              // [8192][1024] bf16, 16 MB

    dim3 b32(32, 8);
    transpose_cast4<<<dim3(32, 32, 4), b32, 0, stream>>>(Wq, Wk, Wv, Wp, wqkv_t, wp_t);
    transpose_cast_w12<<<dim3(128, 32, 2), b32, 0, stream>>>(W1, W2, w1_t, w2_t);

    ln_kernel<<<M_ROWS, 256, 0, stream>>>(x, g1, be1, h_bf);
    gemm_bt128<0><<<dim3(24, 32), 512, 0, stream>>>(h_bf, wqkv_t, M_ROWS, 3072, 1024,
                                                    nullptr, nullptr, (float*)vt_bf, q_bf);
    // attn grid: (bh, pair) = (64, 8) -> same-bh blocks co-locate per XCD
    attn_kernel<<<dim3(64, 8), 512, 0, stream>>>(q_bf, q_bf + 8388608, vt_bf, attn_bf);
    gemm_bt128<2><<<dim3(8, 32), 512, 0, stream>>>(attn_bf, wp_t, M_ROWS, 1024, 1024,
                                                   bp, x, nullptr, x2b);
    ln_kernel_bf<<<M_ROWS, 256, 0, stream>>>(x2b, g2, be2, h_bf);
    gemm_bt256<1><<<dim3(16, 32), 512, 0, stream>>>(h_bf, w1_t, M_ROWS, 4096, 1024, 1024,
                                                    b1, nullptr, nullptr, ff1);
    gemm_bt128<4><<<dim3(8, 32), 512, 0, stream>>>(ff1, w2_t, M_ROWS, 1024, 4096,
                                                   b2, x2b, (float*)d_out, nullptr);
}